// Round 9
// baseline (376.617 us; speedup 1.0000x reference)
//
#include <hip/hip_runtime.h>

#define NN 20000
#define NE 320000
#define NG 256
#define NZ 728            // 7*104
#define NH 104            // 64+24+16
#define NCOMP 216         // 64 + 24*3 + 16*5

static __device__ __forceinline__ unsigned short f2bf(float f) {
    union { float f; unsigned int i; } c; c.f = f;
    unsigned int x = c.i;
    return (unsigned short)((x + 0x7FFFu + ((x >> 16) & 1u)) >> 16);
}
static __device__ __forceinline__ void unpk2(unsigned int w, float& a, float& b) {
    union { unsigned int i; float f; } c0, c1;
    c0.i = w << 16; c1.i = w & 0xFFFF0000u;
    a = c0.f; b = c1.f;
}

// ---------------- K1: blocks [0,1250) count degrees; rest build Wz (24 rows, row23=0) ----------------

__global__ __launch_bounds__(256) void k_count_wz(const int* __restrict__ esrc,
                                                  const int* __restrict__ edst,
                                                  const float* __restrict__ W1,
                                                  const float* __restrict__ W2,
                                                  const float* __restrict__ W3,
                                                  int* __restrict__ deg_src,
                                                  int* __restrict__ deg_dst,
                                                  float* __restrict__ Wz)
{
    const int b = blockIdx.x, t = threadIdx.x;
    if (b < 1250) {
        const int e = b * 256 + t;           // 1250*256 == NE exactly
        atomicAdd(&deg_src[esrc[e]], 1);
        atomicAdd(&deg_dst[edst[e]], 1);
    } else {
        const int idx = (b - 1250) * 256 + t;   // Wz: [u][v*104+w], a1 folded
        if (idx < 24 * NZ) {
            const int u = idx / NZ, c = idx - u * NZ;
            const int v = c / NH, w = c - v * NH;
            float val = 0.f;
            if (u < 23) {
                if (w < 64)      val = W1[(u*7 + v)*64 + w];
                else if (w < 88) val = W2[(u*7 + v)*24 + (w - 64)];
                else             val = W3[(u*7 + v)*16 + (w - 88)];
                val *= 0.07881104f;          // a1 = 1/sqrt(23*7)
            }
            Wz[idx] = val;
        }
    }
}

// ---------------- K2: blocks 0,1 scan degrees (shuffle scan); blocks 2.. node_z ----------------

__global__ __launch_bounds__(256) void k_scan_nodez(const int* __restrict__ deg_src,
                                                    const int* __restrict__ deg_dst,
                                                    const float* __restrict__ x,
                                                    const float* __restrict__ Wz,
                                                    int* __restrict__ offs_src,
                                                    int* __restrict__ cur_src,
                                                    int* __restrict__ offs_dst,
                                                    int* __restrict__ cur_dst,
                                                    float* __restrict__ z)
{
    __shared__ __align__(16) char smem[1024];
    const int b = blockIdx.x, t = threadIdx.x;
    if (b < 2) {
        int* wsum = (int*)smem;                 // [4]
        const int* deg = b ? deg_dst : deg_src;
        int* offs = b ? offs_dst : offs_src;
        int* cur  = b ? cur_dst  : cur_src;
        const int lane = t & 63, wid = t >> 6;
        const int NCH = 79;                     // 79*256 >= 20000
        int run = 0;
        int nextv = (t < NN) ? deg[t] : 0;
        for (int c = 0; c < NCH; ++c) {
            const int j = c * 256 + t;
            const int v = nextv;
            const int jn = j + 256;
            nextv = (c + 1 < NCH && jn < NN) ? deg[jn] : 0;   // prefetch
            int inc = v;
#pragma unroll
            for (int off = 1; off < 64; off <<= 1) {
                const int o = __shfl_up(inc, off, 64);
                if (lane >= off) inc += o;
            }
            if (lane == 63) wsum[wid] = inc;
            __syncthreads();
            int wbase = 0;
#pragma unroll
            for (int wv = 0; wv < 4; ++wv) if (wv < wid) wbase += wsum[wv];
            const int excl = run + wbase + inc - v;
            if (j < NN) { offs[j] = excl; cur[j] = excl; }
            run += wsum[0] + wsum[1] + wsum[2] + wsum[3];
            __syncthreads();
        }
        if (t == 255) offs[NN] = run;
    } else {
        float (*xa)[24] = (float (*)[24])smem;
        const int base = (b - 2) * 8;
        if (t < 192) {
            const int nl = t / 24, u = t - nl * 24;
            xa[nl][u] = (u < 23) ? x[(size_t)(base + nl) * 23 + u] : 0.f;
        }
        __syncthreads();
        const int c0 = t, c1 = t + 256, c2 = t + 512;
        const bool has2 = (c2 < NZ);
        float acc[8][3];
#pragma unroll
        for (int n = 0; n < 8; ++n) { acc[n][0] = 0.f; acc[n][1] = 0.f; acc[n][2] = 0.f; }
#pragma unroll
        for (int u4 = 0; u4 < 24; u4 += 4) {
            float w[4][3];
#pragma unroll
            for (int k = 0; k < 4; ++k) {
                const float* wr = Wz + (u4 + k) * NZ;
                w[k][0] = wr[c0];
                w[k][1] = wr[c1];
                w[k][2] = has2 ? wr[c2] : 0.f;
            }
#pragma unroll
            for (int n = 0; n < 8; ++n) {
                const float4 xv = *(const float4*)&xa[n][u4];
                acc[n][0] += xv.x*w[0][0] + xv.y*w[1][0] + xv.z*w[2][0] + xv.w*w[3][0];
                acc[n][1] += xv.x*w[0][1] + xv.y*w[1][1] + xv.z*w[2][1] + xv.w*w[3][1];
                acc[n][2] += xv.x*w[0][2] + xv.y*w[1][2] + xv.z*w[2][2] + xv.w*w[3][2];
            }
        }
#pragma unroll
        for (int n = 0; n < 8; ++n) {
            float* zo = z + (size_t)(base + n) * NZ;
            zo[c0] = acc[n][0];
            zo[c1] = acc[n][1];
            if (has2) zo[c2] = acc[n][2];
        }
    }
}

// ---------------- K3: fill dual CSR; pre-gather ea (stride 8) and sh (dst order) ----------------

__global__ __launch_bounds__(256) void k_fill(const float* __restrict__ pos,
                                              const float* __restrict__ eag,
                                              const int* __restrict__ esrc,
                                              const int* __restrict__ edst,
                                              int* __restrict__ cur_src,
                                              int* __restrict__ cur_dst,
                                              int* __restrict__ srcq,
                                              int* __restrict__ pq,
                                              float* __restrict__ eaq,
                                              float* __restrict__ shq)
{
    const int e = blockIdx.x * 256 + threadIdx.x;   // grid = 1250 exact
    const int s = esrc[e], d = edst[e];
    const int q = atomicAdd(&cur_src[s], 1);
    const int p = atomicAdd(&cur_dst[d], 1);
    srcq[q] = s;
    pq[q] = p;
    float* o = eaq + (size_t)q * 8;
#pragma unroll
    for (int v = 0; v < 7; ++v) o[v] = eag[(size_t)e * 7 + v];
    o[7] = 0.f;
    const float px = pos[3*s+0] - pos[3*d+0];
    const float py = pos[3*s+1] - pos[3*d+1];
    const float pz = pos[3*s+2] - pos[3*d+2];
    const float r2 = px*px + py*py + pz*pz;
    float* sh = shq + (size_t)p * 8;
    sh[0] = 1.7320508f*px;
    sh[1] = 1.7320508f*py;
    sh[2] = 1.7320508f*pz;
    sh[3] = 3.8729833f*px*py;
    sh[4] = 3.8729833f*py*pz;
    sh[5] = 1.1180340f*(3.f*pz*pz - r2);
    sh[6] = 3.8729833f*px*pz;
    sh[7] = 1.9364917f*(px*px - py*py);
}

// ---------------- K4: per-edge h; lane c computes comps (2c, 2c+1) via ds_read_b64 ----------------
// hbuf dword layout: dword c of a row = bf16 comps (2c low, 2c+1 high)

__global__ __launch_bounds__(256) void k_edge_hb(const float* __restrict__ z,
                                                 const int* __restrict__ offs_src,
                                                 const int* __restrict__ srcq,
                                                 const int* __restrict__ pq,
                                                 const float* __restrict__ eaq,
                                                 unsigned int* __restrict__ hbuf)
{
    __shared__ float zl[8 * NZ];   // 23296 B
    const int t = threadIdx.x;
    const int base = blockIdx.x * 8;
    const float4* zg = (const float4*)(z + (size_t)base * NZ);
    float4* zl4 = (float4*)zl;
    for (int i = t; i < (8 * NZ) / 4; i += 256) zl4[i] = zg[i];
    const int qbeg = offs_src[base], qend = offs_src[base + 8];
    __syncthreads();

    const int lane = t & 63, wid = t >> 6;
    int q = qbeg + wid;
    if (q >= qend) return;
    int slot = srcq[q] - base;
    int p = pq[q];
    float4 eA = ((const float4*)(eaq + (size_t)q * 8))[0];
    float4 eB = ((const float4*)(eaq + (size_t)q * 8))[1];

    while (1) {
        const int qn = q + 4;
        const bool more = qn < qend;
        int slotn = 0, pn = 0;
        float4 eAn = eA, eBn = eB;
        if (more) {
            slotn = srcq[qn] - base;
            pn = pq[qn];
            eAn = ((const float4*)(eaq + (size_t)qn * 8))[0];
            eBn = ((const float4*)(eaq + (size_t)qn * 8))[1];
        }
        if (lane < 52) {
            const float* zr = zl + slot * NZ + 2 * lane;
            const float2 z0 = *(const float2*)&zr[0];
            const float2 z1 = *(const float2*)&zr[104];
            const float2 z2 = *(const float2*)&zr[208];
            const float2 z3 = *(const float2*)&zr[312];
            const float2 z4 = *(const float2*)&zr[416];
            const float2 z5 = *(const float2*)&zr[520];
            const float2 z6 = *(const float2*)&zr[624];
            const float ha = eA.x*z0.x + eA.y*z1.x + eA.z*z2.x + eA.w*z3.x
                           + eB.x*z4.x + eB.y*z5.x + eB.z*z6.x;
            const float hb = eA.x*z0.y + eA.y*z1.y + eA.z*z2.y + eA.w*z3.y
                           + eB.x*z4.y + eB.y*z5.y + eB.z*z6.y;
            hbuf[(size_t)p * 52 + lane] =
                ((unsigned int)f2bf(hb) << 16) | (unsigned int)f2bf(ha);
        }
        if (!more) break;
        slot = slotn; p = pn; eA = eAn; eB = eBn; q = qn;
    }
}

// ---------------- K5: wave-per-node segment-sum + fused V-contraction -> rtab ----------------
// rtab row (64 fp32): [c0*r0[v] (7) | c1*r1[m*7+v] (21) | c2*r2[m*7+v] (35) | pad]

__global__ __launch_bounds__(256) void k_segsum(const unsigned int* __restrict__ hbuf,
                                                const float* __restrict__ shq,
                                                const int* __restrict__ offs_dst,
                                                const float* __restrict__ V1,
                                                const float* __restrict__ V2,
                                                const float* __restrict__ V3,
                                                float* __restrict__ rtab)
{
    __shared__ float ncl[4][224];       // per-wave n components (216 used)
    const int t = threadIdx.x, lane = t & 63, wid = t >> 6;
    const int node = blockIdx.x * 4 + wid;   // grid = 5000 exact
    const int beg = offs_dst[node], end = offs_dst[node + 1];

    // lane c holds h comps (2c, 2c+1):
    //   lanes 0..31  -> comps 0..63   (n0)           : 2 accs
    //   lanes 32..43 -> comps 64..87  (n1, x sh1[m]) : 6 accs
    //   lanes 44..51 -> comps 88..103 (n2, x sh2[m]) : 10 accs
    float acc[10];
#pragma unroll
    for (int i = 0; i < 10; ++i) acc[i] = 0.f;

    for (int r = beg; r < end; ++r) {
        const unsigned int hd = (lane < 52) ? hbuf[(size_t)r * 52 + lane] : 0u;
        const float4 sA = *(const float4*)(shq + (size_t)r * 8);      // sh1[0..2], sh2[0]
        const float4 sB = *(const float4*)(shq + (size_t)r * 8 + 4);  // sh2[1..4]
        float va, vb;
        unpk2(hd, va, vb);
        if (lane < 32) {
            acc[0] += va; acc[1] += vb;
        } else if (lane < 44) {
            acc[0] += va*sA.x; acc[1] += va*sA.y; acc[2] += va*sA.z;
            acc[3] += vb*sA.x; acc[4] += vb*sA.y; acc[5] += vb*sA.z;
        } else if (lane < 52) {
            acc[0] += va*sA.w; acc[1] += va*sB.x; acc[2] += va*sB.y;
            acc[3] += va*sB.z; acc[4] += va*sB.w;
            acc[5] += vb*sA.w; acc[6] += vb*sB.x; acc[7] += vb*sB.y;
            acc[8] += vb*sB.z; acc[9] += vb*sB.w;
        }
    }

    float* nw = ncl[wid];
    if (lane < 32) {
        nw[2*lane] = acc[0];
        nw[2*lane + 1] = acc[1];
    } else if (lane < 44) {
        const int wi = 2 * (lane - 32);
#pragma unroll
        for (int m = 0; m < 3; ++m) {
            nw[64 + wi*3 + m] = acc[m];
            nw[64 + (wi+1)*3 + m] = acc[3 + m];
        }
    } else if (lane < 52) {
        const int wi = 2 * (lane - 44);
#pragma unroll
        for (int m = 0; m < 5; ++m) {
            nw[136 + wi*5 + m] = acc[m];
            nw[136 + (wi+1)*5 + m] = acc[5 + m];
        }
    }
    __syncthreads();    // all waves reach exactly once (loops are ragged but finite)

    float rv = 0.f;
    if (lane < 7) {
        const int v = lane;
#pragma unroll
        for (int u = 0; u < 64; ++u) rv += nw[u] * V1[u*7 + v];
        rv *= 0.04724556f;                    // 1/sqrt(64*7)
    } else if (lane < 28) {
        const int i = lane - 7, m = i / 7, v = i - 7*m;
#pragma unroll
        for (int u = 0; u < 24; ++u) rv += nw[64 + u*3 + m] * V2[u*7 + v];
        rv *= 0.04454354f;                    // 1/sqrt(24*7*3)
    } else if (lane < 63) {
        const int i = lane - 28, m = i / 7, v = i - 7*m;
#pragma unroll
        for (int u = 0; u < 16; ++u) rv += nw[136 + u*5 + m] * V3[u*7 + v];
        rv *= 0.04225771f;                    // 1/sqrt(16*7*5)
    }
    rtab[(size_t)node * 64 + lane] = rv;
}

// ---------------- K6: per-edge g via rtab; scatter to 16-way partial bins ----------------

__global__ __launch_bounds__(256) void k_gfinal(const float* __restrict__ pos,
                                                const float* __restrict__ eag,
                                                const int* __restrict__ esrc,
                                                const int* __restrict__ edst,
                                                const int* __restrict__ batch,
                                                const float* __restrict__ rtab,
                                                float* __restrict__ partial)
{
    const int e = blockIdx.x * 256 + threadIdx.x;   // grid = 1250 exact
    const int s = esrc[e], d = edst[e];
    float ea[7];
#pragma unroll
    for (int v = 0; v < 7; ++v) ea[v] = eag[(size_t)e * 7 + v];
    const float px = pos[3*s+0] - pos[3*d+0];
    const float py = pos[3*s+1] - pos[3*d+1];
    const float pz = pos[3*s+2] - pos[3*d+2];
    const float r2 = px*px + py*py + pz*pz;
    const float s10 = 1.7320508f*px, s11 = 1.7320508f*py, s12 = 1.7320508f*pz;
    const float s20 = 3.8729833f*px*py, s21 = 3.8729833f*py*pz,
                s22 = 1.1180340f*(3.f*pz*pz - r2), s23 = 3.8729833f*px*pz,
                s24 = 1.9364917f*(px*px - py*py);

    float rb[64];
    const float4* rr = (const float4*)(rtab + (size_t)s * 64);
#pragma unroll
    for (int i = 0; i < 16; ++i) *(float4*)&rb[4*i] = rr[i];

    float g = 0.f;
#pragma unroll
    for (int v = 0; v < 7; ++v) {
        const float tv = rb[v]
                       + s10*rb[7+v]  + s11*rb[14+v] + s12*rb[21+v]
                       + s20*rb[28+v] + s21*rb[35+v] + s22*rb[42+v]
                       + s23*rb[49+v] + s24*rb[56+v];
        g += ea[v] * tv;
    }
    unsafeAtomicAdd(&partial[(e & 15) * NG + batch[d]], g);
}

// ---------------- K7: reduce 16 partial rows -> out ----------------

__global__ __launch_bounds__(256) void k_reduce(const float* __restrict__ partial,
                                                float* __restrict__ out)
{
    const int gidx = threadIdx.x;
    float s = 0.f;
#pragma unroll
    for (int i = 0; i < 16; ++i) s += partial[i * NG + gidx];
    out[gidx] = s;
}

extern "C" void kernel_launch(void* const* d_in, const int* in_sizes, int n_in,
                              void* d_out, int out_size, void* d_ws, size_t ws_size,
                              hipStream_t stream)
{
    const float* pos  = (const float*)d_in[0];
    const float* x    = (const float*)d_in[1];
    const float* eag  = (const float*)d_in[2];
    const int*   eidx = (const int*)d_in[3];
    const int*   batch= (const int*)d_in[4];
    const float* W1   = (const float*)d_in[5];
    const float* W2   = (const float*)d_in[6];
    const float* W3   = (const float*)d_in[7];
    const float* V1   = (const float*)d_in[8];
    const float* V2   = (const float*)d_in[9];
    const float* V3   = (const float*)d_in[10];
    const int* esrc = eidx;
    const int* edst = eidx + NE;

    char* ws = (char*)d_ws;
    size_t off = 0;
    auto alloc = [&](size_t bytes) -> void* {
        void* p = ws + off;
        off = (off + bytes + 255) & ~(size_t)255;
        return p;
    };
    float* z        = (float*)alloc((size_t)NN * NZ * sizeof(float));        // 58.2 MB
    unsigned int* hbuf = (unsigned int*)alloc((size_t)NE * 52 * sizeof(unsigned int)); // 66.6 MB
    float* shq      = (float*)alloc((size_t)NE * 8 * sizeof(float));         // 10.2 MB
    float* eaq      = (float*)alloc((size_t)NE * 8 * sizeof(float));         // 10.2 MB
    float* rtab     = (float*)alloc((size_t)NN * 64 * sizeof(float));        // 5.1 MB
    int*   srcq     = (int*)alloc((size_t)NE * sizeof(int));
    int*   pq       = (int*)alloc((size_t)NE * sizeof(int));
    float* Wz       = (float*)alloc((size_t)24 * NZ * sizeof(float));
    int*   deg_src  = (int*)alloc((size_t)NN * sizeof(int));     // ---- zeroed region start
    int*   deg_dst  = (int*)alloc((size_t)NN * sizeof(int));
    float* partial  = (float*)alloc((size_t)16 * NG * sizeof(float));
    int*   offs_src = (int*)alloc((size_t)(NN + 1) * sizeof(int));  // ---- zeroed region end
    int*   offs_dst = (int*)alloc((size_t)(NN + 1) * sizeof(int));
    int*   cur_src  = (int*)alloc((size_t)NN * sizeof(int));
    int*   cur_dst  = (int*)alloc((size_t)NN * sizeof(int));

    hipMemsetAsync(deg_src, 0, (size_t)((char*)offs_src - (char*)deg_src), stream);

    k_count_wz<<<1250 + 69, 256, 0, stream>>>(esrc, edst, W1, W2, W3,
                                              deg_src, deg_dst, Wz);
    k_scan_nodez<<<2 + 2500, 256, 0, stream>>>(deg_src, deg_dst, x, Wz,
                                               offs_src, cur_src, offs_dst, cur_dst, z);
    k_fill<<<1250, 256, 0, stream>>>(pos, eag, esrc, edst, cur_src, cur_dst,
                                     srcq, pq, eaq, shq);
    k_edge_hb<<<NN/8, 256, 0, stream>>>(z, offs_src, srcq, pq, eaq, hbuf);
    k_segsum<<<NN/4, 256, 0, stream>>>(hbuf, shq, offs_dst, V1, V2, V3, rtab);
    k_gfinal<<<1250, 256, 0, stream>>>(pos, eag, esrc, edst, batch, rtab, partial);
    k_reduce<<<1, 256, 0, stream>>>(partial, (float*)d_out);
}

// Round 10
// 347.227 us; speedup vs baseline: 1.0846x; 1.0846x over previous
//
#include <hip/hip_runtime.h>

#define NN 20000
#define NE 320000
#define NG 256
#define NZ 728            // 7*104
#define NH 104            // 64+24+16
#define NCOMP 216         // 64 + 24*3 + 16*5

static __device__ __forceinline__ unsigned short f2bf(float f) {
    union { float f; unsigned int i; } c; c.f = f;
    unsigned int x = c.i;
    return (unsigned short)((x + 0x7FFFu + ((x >> 16) & 1u)) >> 16);
}
static __device__ __forceinline__ void unpk2(unsigned int w, float& a, float& b) {
    union { unsigned int i; float f; } c0, c1;
    c0.i = w << 16; c1.i = w & 0xFFFF0000u;
    a = c0.f; b = c1.f;
}

// ---------------- K1: blocks [0,1250) count degrees; rest build Wz (24 rows, row23=0) ----------------

__global__ __launch_bounds__(256) void k_count_wz(const int* __restrict__ esrc,
                                                  const int* __restrict__ edst,
                                                  const float* __restrict__ W1,
                                                  const float* __restrict__ W2,
                                                  const float* __restrict__ W3,
                                                  int* __restrict__ deg_src,
                                                  int* __restrict__ deg_dst,
                                                  float* __restrict__ Wz)
{
    const int b = blockIdx.x, t = threadIdx.x;
    if (b < 1250) {
        const int e = b * 256 + t;           // 1250*256 == NE exactly
        atomicAdd(&deg_src[esrc[e]], 1);
        atomicAdd(&deg_dst[edst[e]], 1);
    } else {
        const int idx = (b - 1250) * 256 + t;   // Wz: [u][v*104+w], a1 folded
        if (idx < 24 * NZ) {
            const int u = idx / NZ, c = idx - u * NZ;
            const int v = c / NH, w = c - v * NH;
            float val = 0.f;
            if (u < 23) {
                if (w < 64)      val = W1[(u*7 + v)*64 + w];
                else if (w < 88) val = W2[(u*7 + v)*24 + (w - 64)];
                else             val = W3[(u*7 + v)*16 + (w - 88)];
                val *= 0.07881104f;          // a1 = 1/sqrt(23*7)
            }
            Wz[idx] = val;
        }
    }
}

// ---------------- K2: blocks 0,1 scan degrees (shuffle scan); blocks 2.. node_z ----------------

__global__ __launch_bounds__(256) void k_scan_nodez(const int* __restrict__ deg_src,
                                                    const int* __restrict__ deg_dst,
                                                    const float* __restrict__ x,
                                                    const float* __restrict__ Wz,
                                                    int* __restrict__ offs_src,
                                                    int* __restrict__ cur_src,
                                                    int* __restrict__ offs_dst,
                                                    int* __restrict__ cur_dst,
                                                    float* __restrict__ z)
{
    __shared__ __align__(16) char smem[1024];
    const int b = blockIdx.x, t = threadIdx.x;
    if (b < 2) {
        int* wsum = (int*)smem;                 // [4]
        const int* deg = b ? deg_dst : deg_src;
        int* offs = b ? offs_dst : offs_src;
        int* cur  = b ? cur_dst  : cur_src;
        const int lane = t & 63, wid = t >> 6;
        const int NCH = 79;                     // 79*256 >= 20000
        int run = 0;
        int nextv = (t < NN) ? deg[t] : 0;
        for (int c = 0; c < NCH; ++c) {
            const int j = c * 256 + t;
            const int v = nextv;
            const int jn = j + 256;
            nextv = (c + 1 < NCH && jn < NN) ? deg[jn] : 0;   // prefetch
            int inc = v;
#pragma unroll
            for (int off = 1; off < 64; off <<= 1) {
                const int o = __shfl_up(inc, off, 64);
                if (lane >= off) inc += o;
            }
            if (lane == 63) wsum[wid] = inc;
            __syncthreads();
            int wbase = 0;
#pragma unroll
            for (int wv = 0; wv < 4; ++wv) if (wv < wid) wbase += wsum[wv];
            const int excl = run + wbase + inc - v;
            if (j < NN) { offs[j] = excl; cur[j] = excl; }
            run += wsum[0] + wsum[1] + wsum[2] + wsum[3];
            __syncthreads();
        }
        if (t == 255) offs[NN] = run;
    } else {
        float (*xa)[24] = (float (*)[24])smem;
        const int base = (b - 2) * 8;
        if (t < 192) {
            const int nl = t / 24, u = t - nl * 24;
            xa[nl][u] = (u < 23) ? x[(size_t)(base + nl) * 23 + u] : 0.f;
        }
        __syncthreads();
        const int c0 = t, c1 = t + 256, c2 = t + 512;
        const bool has2 = (c2 < NZ);
        float acc[8][3];
#pragma unroll
        for (int n = 0; n < 8; ++n) { acc[n][0] = 0.f; acc[n][1] = 0.f; acc[n][2] = 0.f; }
#pragma unroll
        for (int u4 = 0; u4 < 24; u4 += 4) {
            float w[4][3];
#pragma unroll
            for (int k = 0; k < 4; ++k) {
                const float* wr = Wz + (u4 + k) * NZ;
                w[k][0] = wr[c0];
                w[k][1] = wr[c1];
                w[k][2] = has2 ? wr[c2] : 0.f;
            }
#pragma unroll
            for (int n = 0; n < 8; ++n) {
                const float4 xv = *(const float4*)&xa[n][u4];
                acc[n][0] += xv.x*w[0][0] + xv.y*w[1][0] + xv.z*w[2][0] + xv.w*w[3][0];
                acc[n][1] += xv.x*w[0][1] + xv.y*w[1][1] + xv.z*w[2][1] + xv.w*w[3][1];
                acc[n][2] += xv.x*w[0][2] + xv.y*w[1][2] + xv.z*w[2][2] + xv.w*w[3][2];
            }
        }
#pragma unroll
        for (int n = 0; n < 8; ++n) {
            float* zo = z + (size_t)(base + n) * NZ;
            zo[c0] = acc[n][0];
            zo[c1] = acc[n][1];
            if (has2) zo[c2] = acc[n][2];
        }
    }
}

// ---------------- K3: fill dual CSR; pre-gather ea (stride 8) and sh (dst order) ----------------

__global__ __launch_bounds__(256) void k_fill(const float* __restrict__ pos,
                                              const float* __restrict__ eag,
                                              const int* __restrict__ esrc,
                                              const int* __restrict__ edst,
                                              int* __restrict__ cur_src,
                                              int* __restrict__ cur_dst,
                                              int* __restrict__ srcq,
                                              int* __restrict__ pq,
                                              float* __restrict__ eaq,
                                              float* __restrict__ shq)
{
    const int e = blockIdx.x * 256 + threadIdx.x;   // grid = 1250 exact
    const int s = esrc[e], d = edst[e];
    const int q = atomicAdd(&cur_src[s], 1);
    const int p = atomicAdd(&cur_dst[d], 1);
    srcq[q] = s;
    pq[q] = p;
    float* o = eaq + (size_t)q * 8;
#pragma unroll
    for (int v = 0; v < 7; ++v) o[v] = eag[(size_t)e * 7 + v];
    o[7] = 0.f;
    const float px = pos[3*s+0] - pos[3*d+0];
    const float py = pos[3*s+1] - pos[3*d+1];
    const float pz = pos[3*s+2] - pos[3*d+2];
    const float r2 = px*px + py*py + pz*pz;
    float* sh = shq + (size_t)p * 8;
    sh[0] = 1.7320508f*px;
    sh[1] = 1.7320508f*py;
    sh[2] = 1.7320508f*pz;
    sh[3] = 3.8729833f*px*py;
    sh[4] = 3.8729833f*py*pz;
    sh[5] = 1.1180340f*(3.f*pz*pz - r2);
    sh[6] = 3.8729833f*px*pz;
    sh[7] = 1.9364917f*(px*px - py*py);
}

// ---------------- K4: per-edge h; lane c computes comps (2c, 2c+1) via ds_read_b64 ----------------
// hbuf dword layout: dword c of a row = bf16 comps (2c low, 2c+1 high)

__global__ __launch_bounds__(256) void k_edge_hb(const float* __restrict__ z,
                                                 const int* __restrict__ offs_src,
                                                 const int* __restrict__ srcq,
                                                 const int* __restrict__ pq,
                                                 const float* __restrict__ eaq,
                                                 unsigned int* __restrict__ hbuf)
{
    __shared__ float zl[8 * NZ];   // 23296 B
    const int t = threadIdx.x;
    const int base = blockIdx.x * 8;
    const float4* zg = (const float4*)(z + (size_t)base * NZ);
    float4* zl4 = (float4*)zl;
    for (int i = t; i < (8 * NZ) / 4; i += 256) zl4[i] = zg[i];
    const int qbeg = offs_src[base], qend = offs_src[base + 8];
    __syncthreads();

    const int lane = t & 63, wid = t >> 6;
    int q = qbeg + wid;
    if (q >= qend) return;
    int slot = srcq[q] - base;
    int p = pq[q];
    float4 eA = ((const float4*)(eaq + (size_t)q * 8))[0];
    float4 eB = ((const float4*)(eaq + (size_t)q * 8))[1];

    while (1) {
        const int qn = q + 4;
        const bool more = qn < qend;
        int slotn = 0, pn = 0;
        float4 eAn = eA, eBn = eB;
        if (more) {
            slotn = srcq[qn] - base;
            pn = pq[qn];
            eAn = ((const float4*)(eaq + (size_t)qn * 8))[0];
            eBn = ((const float4*)(eaq + (size_t)qn * 8))[1];
        }
        if (lane < 52) {
            const float* zr = zl + slot * NZ + 2 * lane;
            const float2 z0 = *(const float2*)&zr[0];
            const float2 z1 = *(const float2*)&zr[104];
            const float2 z2 = *(const float2*)&zr[208];
            const float2 z3 = *(const float2*)&zr[312];
            const float2 z4 = *(const float2*)&zr[416];
            const float2 z5 = *(const float2*)&zr[520];
            const float2 z6 = *(const float2*)&zr[624];
            const float ha = eA.x*z0.x + eA.y*z1.x + eA.z*z2.x + eA.w*z3.x
                           + eB.x*z4.x + eB.y*z5.x + eB.z*z6.x;
            const float hb = eA.x*z0.y + eA.y*z1.y + eA.z*z2.y + eA.w*z3.y
                           + eB.x*z4.y + eB.y*z5.y + eB.z*z6.y;
            hbuf[(size_t)p * 52 + lane] =
                ((unsigned int)f2bf(hb) << 16) | (unsigned int)f2bf(ha);
        }
        if (!more) break;
        slot = slotn; p = pn; eA = eAn; eB = eBn; q = qn;
    }
}

// ---------------- K5: wave-per-node segment-sum (4-row pipelined) + fused V-contraction ----------------
// rtab row (64 fp32): [c0*r0[v] (7) | c1*r1[m*7+v] (21) | c2*r2[m*7+v] (35) | pad]

__global__ __launch_bounds__(256) void k_segsum(const unsigned int* __restrict__ hbuf,
                                                const float* __restrict__ shq,
                                                const int* __restrict__ offs_dst,
                                                const float* __restrict__ V1,
                                                const float* __restrict__ V2,
                                                const float* __restrict__ V3,
                                                float* __restrict__ rtab)
{
    __shared__ float ncl[4][224];       // per-wave n components (216 used)
    const int t = threadIdx.x, lane = t & 63, wid = t >> 6;
    const int node = blockIdx.x * 4 + wid;   // grid = 5000 exact
    const int beg = offs_dst[node], end = offs_dst[node + 1];

    // lane c holds h comps (2c, 2c+1):
    //   lanes 0..31  -> comps 0..63   (n0)           : 2 accs
    //   lanes 32..43 -> comps 64..87  (n1, x sh1[m]) : 6 accs
    //   lanes 44..51 -> comps 88..103 (n2, x sh2[m]) : 10 accs
    float acc[10];
#pragma unroll
    for (int i = 0; i < 10; ++i) acc[i] = 0.f;
    const bool hasld = (lane < 52);

#define ACCUM(HD, SA, SB)                                                     \
    do {                                                                      \
        float va, vb;                                                         \
        unpk2(HD, va, vb);                                                    \
        if (lane < 32) {                                                      \
            acc[0] += va; acc[1] += vb;                                       \
        } else if (lane < 44) {                                               \
            acc[0] += va*(SA).x; acc[1] += va*(SA).y; acc[2] += va*(SA).z;    \
            acc[3] += vb*(SA).x; acc[4] += vb*(SA).y; acc[5] += vb*(SA).z;    \
        } else if (lane < 52) {                                               \
            acc[0] += va*(SA).w; acc[1] += va*(SB).x; acc[2] += va*(SB).y;    \
            acc[3] += va*(SB).z; acc[4] += va*(SB).w;                         \
            acc[5] += vb*(SA).w; acc[6] += vb*(SB).x; acc[7] += vb*(SB).y;    \
            acc[8] += vb*(SB).z; acc[9] += vb*(SB).w;                         \
        }                                                                     \
    } while (0)

    int r = beg;
    for (; r + 4 <= end; r += 4) {
        // issue all 12 loads before any use: 4 vector + 8 wave-uniform (scalar)
        const unsigned int hd0 = hasld ? hbuf[(size_t)(r+0) * 52 + lane] : 0u;
        const unsigned int hd1 = hasld ? hbuf[(size_t)(r+1) * 52 + lane] : 0u;
        const unsigned int hd2 = hasld ? hbuf[(size_t)(r+2) * 52 + lane] : 0u;
        const unsigned int hd3 = hasld ? hbuf[(size_t)(r+3) * 52 + lane] : 0u;
        const float4 sA0 = *(const float4*)(shq + (size_t)(r+0) * 8);
        const float4 sB0 = *(const float4*)(shq + (size_t)(r+0) * 8 + 4);
        const float4 sA1 = *(const float4*)(shq + (size_t)(r+1) * 8);
        const float4 sB1 = *(const float4*)(shq + (size_t)(r+1) * 8 + 4);
        const float4 sA2 = *(const float4*)(shq + (size_t)(r+2) * 8);
        const float4 sB2 = *(const float4*)(shq + (size_t)(r+2) * 8 + 4);
        const float4 sA3 = *(const float4*)(shq + (size_t)(r+3) * 8);
        const float4 sB3 = *(const float4*)(shq + (size_t)(r+3) * 8 + 4);
        ACCUM(hd0, sA0, sB0);
        ACCUM(hd1, sA1, sB1);
        ACCUM(hd2, sA2, sB2);
        ACCUM(hd3, sA3, sB3);
    }
    for (; r < end; ++r) {
        const unsigned int hd = hasld ? hbuf[(size_t)r * 52 + lane] : 0u;
        const float4 sA = *(const float4*)(shq + (size_t)r * 8);
        const float4 sB = *(const float4*)(shq + (size_t)r * 8 + 4);
        ACCUM(hd, sA, sB);
    }
#undef ACCUM

    float* nw = ncl[wid];
    if (lane < 32) {
        nw[2*lane] = acc[0];
        nw[2*lane + 1] = acc[1];
    } else if (lane < 44) {
        const int wi = 2 * (lane - 32);
#pragma unroll
        for (int m = 0; m < 3; ++m) {
            nw[64 + wi*3 + m] = acc[m];
            nw[64 + (wi+1)*3 + m] = acc[3 + m];
        }
    } else if (lane < 52) {
        const int wi = 2 * (lane - 44);
#pragma unroll
        for (int m = 0; m < 5; ++m) {
            nw[136 + wi*5 + m] = acc[m];
            nw[136 + (wi+1)*5 + m] = acc[5 + m];
        }
    }
    __syncthreads();    // all waves reach exactly once

    float rv = 0.f;
    if (lane < 7) {
        const int v = lane;
#pragma unroll
        for (int u = 0; u < 64; ++u) rv += nw[u] * V1[u*7 + v];
        rv *= 0.04724556f;                    // 1/sqrt(64*7)
    } else if (lane < 28) {
        const int i = lane - 7, m = i / 7, v = i - 7*m;
#pragma unroll
        for (int u = 0; u < 24; ++u) rv += nw[64 + u*3 + m] * V2[u*7 + v];
        rv *= 0.04454354f;                    // 1/sqrt(24*7*3)
    } else if (lane < 63) {
        const int i = lane - 28, m = i / 7, v = i - 7*m;
#pragma unroll
        for (int u = 0; u < 16; ++u) rv += nw[136 + u*5 + m] * V3[u*7 + v];
        rv *= 0.04225771f;                    // 1/sqrt(16*7*5)
    }
    rtab[(size_t)node * 64 + lane] = rv;
}

// ---------------- K6: per-edge g via rtab; scatter to 16-way partial bins ----------------

__global__ __launch_bounds__(256) void k_gfinal(const float* __restrict__ pos,
                                                const float* __restrict__ eag,
                                                const int* __restrict__ esrc,
                                                const int* __restrict__ edst,
                                                const int* __restrict__ batch,
                                                const float* __restrict__ rtab,
                                                float* __restrict__ partial)
{
    const int e = blockIdx.x * 256 + threadIdx.x;   // grid = 1250 exact
    const int s = esrc[e], d = edst[e];
    float ea[7];
#pragma unroll
    for (int v = 0; v < 7; ++v) ea[v] = eag[(size_t)e * 7 + v];
    const float px = pos[3*s+0] - pos[3*d+0];
    const float py = pos[3*s+1] - pos[3*d+1];
    const float pz = pos[3*s+2] - pos[3*d+2];
    const float r2 = px*px + py*py + pz*pz;
    const float s10 = 1.7320508f*px, s11 = 1.7320508f*py, s12 = 1.7320508f*pz;
    const float s20 = 3.8729833f*px*py, s21 = 3.8729833f*py*pz,
                s22 = 1.1180340f*(3.f*pz*pz - r2), s23 = 3.8729833f*px*pz,
                s24 = 1.9364917f*(px*px - py*py);

    float rb[64];
    const float4* rr = (const float4*)(rtab + (size_t)s * 64);
#pragma unroll
    for (int i = 0; i < 16; ++i) *(float4*)&rb[4*i] = rr[i];

    float g = 0.f;
#pragma unroll
    for (int v = 0; v < 7; ++v) {
        const float tv = rb[v]
                       + s10*rb[7+v]  + s11*rb[14+v] + s12*rb[21+v]
                       + s20*rb[28+v] + s21*rb[35+v] + s22*rb[42+v]
                       + s23*rb[49+v] + s24*rb[56+v];
        g += ea[v] * tv;
    }
    unsafeAtomicAdd(&partial[(e & 15) * NG + batch[d]], g);
}

// ---------------- K7: reduce 16 partial rows -> out ----------------

__global__ __launch_bounds__(256) void k_reduce(const float* __restrict__ partial,
                                                float* __restrict__ out)
{
    const int gidx = threadIdx.x;
    float s = 0.f;
#pragma unroll
    for (int i = 0; i < 16; ++i) s += partial[i * NG + gidx];
    out[gidx] = s;
}

extern "C" void kernel_launch(void* const* d_in, const int* in_sizes, int n_in,
                              void* d_out, int out_size, void* d_ws, size_t ws_size,
                              hipStream_t stream)
{
    const float* pos  = (const float*)d_in[0];
    const float* x    = (const float*)d_in[1];
    const float* eag  = (const float*)d_in[2];
    const int*   eidx = (const int*)d_in[3];
    const int*   batch= (const int*)d_in[4];
    const float* W1   = (const float*)d_in[5];
    const float* W2   = (const float*)d_in[6];
    const float* W3   = (const float*)d_in[7];
    const float* V1   = (const float*)d_in[8];
    const float* V2   = (const float*)d_in[9];
    const float* V3   = (const float*)d_in[10];
    const int* esrc = eidx;
    const int* edst = eidx + NE;

    char* ws = (char*)d_ws;
    size_t off = 0;
    auto alloc = [&](size_t bytes) -> void* {
        void* p = ws + off;
        off = (off + bytes + 255) & ~(size_t)255;
        return p;
    };
    float* z        = (float*)alloc((size_t)NN * NZ * sizeof(float));        // 58.2 MB
    unsigned int* hbuf = (unsigned int*)alloc((size_t)NE * 52 * sizeof(unsigned int)); // 66.6 MB
    float* shq      = (float*)alloc((size_t)NE * 8 * sizeof(float));         // 10.2 MB
    float* eaq      = (float*)alloc((size_t)NE * 8 * sizeof(float));         // 10.2 MB
    float* rtab     = (float*)alloc((size_t)NN * 64 * sizeof(float));        // 5.1 MB
    int*   srcq     = (int*)alloc((size_t)NE * sizeof(int));
    int*   pq       = (int*)alloc((size_t)NE * sizeof(int));
    float* Wz       = (float*)alloc((size_t)24 * NZ * sizeof(float));
    int*   deg_src  = (int*)alloc((size_t)NN * sizeof(int));     // ---- zeroed region start
    int*   deg_dst  = (int*)alloc((size_t)NN * sizeof(int));
    float* partial  = (float*)alloc((size_t)16 * NG * sizeof(float));
    int*   offs_src = (int*)alloc((size_t)(NN + 1) * sizeof(int));  // ---- zeroed region end
    int*   offs_dst = (int*)alloc((size_t)(NN + 1) * sizeof(int));
    int*   cur_src  = (int*)alloc((size_t)NN * sizeof(int));
    int*   cur_dst  = (int*)alloc((size_t)NN * sizeof(int));

    hipMemsetAsync(deg_src, 0, (size_t)((char*)offs_src - (char*)deg_src), stream);

    k_count_wz<<<1250 + 69, 256, 0, stream>>>(esrc, edst, W1, W2, W3,
                                              deg_src, deg_dst, Wz);
    k_scan_nodez<<<2 + 2500, 256, 0, stream>>>(deg_src, deg_dst, x, Wz,
                                               offs_src, cur_src, offs_dst, cur_dst, z);
    k_fill<<<1250, 256, 0, stream>>>(pos, eag, esrc, edst, cur_src, cur_dst,
                                     srcq, pq, eaq, shq);
    k_edge_hb<<<NN/8, 256, 0, stream>>>(z, offs_src, srcq, pq, eaq, hbuf);
    k_segsum<<<NN/4, 256, 0, stream>>>(hbuf, shq, offs_dst, V1, V2, V3, rtab);
    k_gfinal<<<1250, 256, 0, stream>>>(pos, eag, esrc, edst, batch, rtab, partial);
    k_reduce<<<1, 256, 0, stream>>>(partial, (float*)d_out);
}

// Round 11
// 328.467 us; speedup vs baseline: 1.1466x; 1.0571x over previous
//
#include <hip/hip_runtime.h>

#define NN 20000
#define NE 320000
#define NG 256
#define NZ 728            // 7*104
#define NH 104            // 64+24+16
#define NCOMP 216         // 64 + 24*3 + 16*5

static __device__ __forceinline__ unsigned short f2bf(float f) {
    union { float f; unsigned int i; } c; c.f = f;
    unsigned int x = c.i;
    return (unsigned short)((x + 0x7FFFu + ((x >> 16) & 1u)) >> 16);
}
static __device__ __forceinline__ unsigned int pk2(float a, float b) {
    return ((unsigned int)f2bf(b) << 16) | (unsigned int)f2bf(a);
}
static __device__ __forceinline__ void unpk2(unsigned int w, float& a, float& b) {
    union { unsigned int i; float f; } c0, c1;
    c0.i = w << 16; c1.i = w & 0xFFFF0000u;
    a = c0.f; b = c1.f;
}

// ---------------- K1: blocks [0,1250) count degrees; rest build Wz (24 rows, row23=0) ----------------

__global__ __launch_bounds__(256) void k_count_wz(const int* __restrict__ esrc,
                                                  const int* __restrict__ edst,
                                                  const float* __restrict__ W1,
                                                  const float* __restrict__ W2,
                                                  const float* __restrict__ W3,
                                                  int* __restrict__ deg_src,
                                                  int* __restrict__ deg_dst,
                                                  float* __restrict__ Wz)
{
    const int b = blockIdx.x, t = threadIdx.x;
    if (b < 1250) {
        const int e = b * 256 + t;           // 1250*256 == NE exactly
        atomicAdd(&deg_src[esrc[e]], 1);
        atomicAdd(&deg_dst[edst[e]], 1);
    } else {
        const int idx = (b - 1250) * 256 + t;   // Wz: [u][v*104+w], a1 folded
        if (idx < 24 * NZ) {
            const int u = idx / NZ, c = idx - u * NZ;
            const int v = c / NH, w = c - v * NH;
            float val = 0.f;
            if (u < 23) {
                if (w < 64)      val = W1[(u*7 + v)*64 + w];
                else if (w < 88) val = W2[(u*7 + v)*24 + (w - 64)];
                else             val = W3[(u*7 + v)*16 + (w - 88)];
                val *= 0.07881104f;          // a1 = 1/sqrt(23*7)
            }
            Wz[idx] = val;
        }
    }
}

// ---------------- K2: blocks 0,1 scan degrees (shuffle scan); blocks 2.. node_z ----------------

__global__ __launch_bounds__(256) void k_scan_nodez(const int* __restrict__ deg_src,
                                                    const int* __restrict__ deg_dst,
                                                    const float* __restrict__ x,
                                                    const float* __restrict__ Wz,
                                                    int* __restrict__ offs_src,
                                                    int* __restrict__ cur_src,
                                                    int* __restrict__ offs_dst,
                                                    int* __restrict__ cur_dst,
                                                    float* __restrict__ z)
{
    __shared__ __align__(16) char smem[1024];
    const int b = blockIdx.x, t = threadIdx.x;
    if (b < 2) {
        int* wsum = (int*)smem;                 // [4]
        const int* deg = b ? deg_dst : deg_src;
        int* offs = b ? offs_dst : offs_src;
        int* cur  = b ? cur_dst  : cur_src;
        const int lane = t & 63, wid = t >> 6;
        const int NCH = 79;                     // 79*256 >= 20000
        int run = 0;
        int nextv = (t < NN) ? deg[t] : 0;
        for (int c = 0; c < NCH; ++c) {
            const int j = c * 256 + t;
            const int v = nextv;
            const int jn = j + 256;
            nextv = (c + 1 < NCH && jn < NN) ? deg[jn] : 0;   // prefetch
            int inc = v;
#pragma unroll
            for (int off = 1; off < 64; off <<= 1) {
                const int o = __shfl_up(inc, off, 64);
                if (lane >= off) inc += o;
            }
            if (lane == 63) wsum[wid] = inc;
            __syncthreads();
            int wbase = 0;
#pragma unroll
            for (int wv = 0; wv < 4; ++wv) if (wv < wid) wbase += wsum[wv];
            const int excl = run + wbase + inc - v;
            if (j < NN) { offs[j] = excl; cur[j] = excl; }
            run += wsum[0] + wsum[1] + wsum[2] + wsum[3];
            __syncthreads();
        }
        if (t == 255) offs[NN] = run;
    } else {
        float (*xa)[24] = (float (*)[24])smem;
        const int base = (b - 2) * 8;
        if (t < 192) {
            const int nl = t / 24, u = t - nl * 24;
            xa[nl][u] = (u < 23) ? x[(size_t)(base + nl) * 23 + u] : 0.f;
        }
        __syncthreads();
        const int c0 = t, c1 = t + 256, c2 = t + 512;
        const bool has2 = (c2 < NZ);
        float acc[8][3];
#pragma unroll
        for (int n = 0; n < 8; ++n) { acc[n][0] = 0.f; acc[n][1] = 0.f; acc[n][2] = 0.f; }
#pragma unroll
        for (int u4 = 0; u4 < 24; u4 += 4) {
            float w[4][3];
#pragma unroll
            for (int k = 0; k < 4; ++k) {
                const float* wr = Wz + (u4 + k) * NZ;
                w[k][0] = wr[c0];
                w[k][1] = wr[c1];
                w[k][2] = has2 ? wr[c2] : 0.f;
            }
#pragma unroll
            for (int n = 0; n < 8; ++n) {
                const float4 xv = *(const float4*)&xa[n][u4];
                acc[n][0] += xv.x*w[0][0] + xv.y*w[1][0] + xv.z*w[2][0] + xv.w*w[3][0];
                acc[n][1] += xv.x*w[0][1] + xv.y*w[1][1] + xv.z*w[2][1] + xv.w*w[3][1];
                acc[n][2] += xv.x*w[0][2] + xv.y*w[1][2] + xv.z*w[2][2] + xv.w*w[3][2];
            }
        }
#pragma unroll
        for (int n = 0; n < 8; ++n) {
            float* zo = z + (size_t)(base + n) * NZ;
            zo[c0] = acc[n][0];
            zo[c1] = acc[n][1];
            if (has2) zo[c2] = acc[n][2];
        }
    }
}

// ---------------- K3: fill dual CSR; pre-gather ea (stride 8) and sh (dst order) ----------------

__global__ __launch_bounds__(256) void k_fill(const float* __restrict__ pos,
                                              const float* __restrict__ eag,
                                              const int* __restrict__ esrc,
                                              const int* __restrict__ edst,
                                              int* __restrict__ cur_src,
                                              int* __restrict__ cur_dst,
                                              int* __restrict__ srcq,
                                              int* __restrict__ pq,
                                              float* __restrict__ eaq,
                                              float* __restrict__ shq)
{
    const int e = blockIdx.x * 256 + threadIdx.x;   // grid = 1250 exact
    const int s = esrc[e], d = edst[e];
    const int q = atomicAdd(&cur_src[s], 1);
    const int p = atomicAdd(&cur_dst[d], 1);
    srcq[q] = s;
    pq[q] = p;
    float* o = eaq + (size_t)q * 8;
#pragma unroll
    for (int v = 0; v < 7; ++v) o[v] = eag[(size_t)e * 7 + v];
    o[7] = 0.f;
    const float px = pos[3*s+0] - pos[3*d+0];
    const float py = pos[3*s+1] - pos[3*d+1];
    const float pz = pos[3*s+2] - pos[3*d+2];
    const float r2 = px*px + py*py + pz*pz;
    float* sh = shq + (size_t)p * 8;
    sh[0] = 1.7320508f*px;
    sh[1] = 1.7320508f*py;
    sh[2] = 1.7320508f*pz;
    sh[3] = 3.8729833f*px*py;
    sh[4] = 3.8729833f*py*pz;
    sh[5] = 1.1180340f*(3.f*pz*pz - r2);
    sh[6] = 3.8729833f*px*pz;
    sh[7] = 1.9364917f*(px*px - py*py);
}

// ---------------- K4: per-edge h; half-wave edge pairing, b128 LDS reads ----------------
// Half-wave: lanes 0-31 = edge A (q), lanes 32-63 = edge B (q+1); lane c<26 computes
// comps 4c..4c+3 via 7 ds_read_b128, stores uint2 (dwords 2c, 2c+1 of the row).
// hbuf dword layout unchanged: dword d of a row = bf16 comps (2d low, 2d+1 high).

__global__ __launch_bounds__(256) void k_edge_hb(const float* __restrict__ z,
                                                 const int* __restrict__ offs_src,
                                                 const int* __restrict__ srcq,
                                                 const int* __restrict__ pq,
                                                 const float* __restrict__ eaq,
                                                 unsigned int* __restrict__ hbuf)
{
    __shared__ float zl[8 * NZ];   // 23296 B
    const int t = threadIdx.x;
    const int base = blockIdx.x * 8;
    const float4* zg = (const float4*)(z + (size_t)base * NZ);
    float4* zl4 = (float4*)zl;
    for (int i = t; i < (8 * NZ) / 4; i += 256) zl4[i] = zg[i];
    const int qbeg = offs_src[base], qend = offs_src[base + 8];
    __syncthreads();

    const int lane = t & 63, wid = t >> 6;
    const int sub = lane >> 5;          // half-wave id (edge A/B)
    const int c = lane & 31;            // 0..31; active c < 26

    int qA = qbeg + 2 * wid;            // wave-uniform pair base, stride 8
    if (qA >= qend) return;
    int myq = qA + sub;
    int slot = 0, p = 0;
    float4 eA = make_float4(0.f,0.f,0.f,0.f), eB = eA;
    if (myq < qend) {
        slot = srcq[myq] - base;
        p = pq[myq];
        eA = ((const float4*)(eaq + (size_t)myq * 8))[0];
        eB = ((const float4*)(eaq + (size_t)myq * 8))[1];
    }

    while (1) {
        const int qA2 = qA + 8;
        const bool more = qA2 < qend;
        const int myq2 = qA2 + sub;
        int slot2 = 0, p2 = 0;
        float4 eA2 = eA, eB2 = eB;
        if (more && myq2 < qend) {
            slot2 = srcq[myq2] - base;
            p2 = pq[myq2];
            eA2 = ((const float4*)(eaq + (size_t)myq2 * 8))[0];
            eB2 = ((const float4*)(eaq + (size_t)myq2 * 8))[1];
        }
        if (myq < qend && c < 26) {
            const float* zr = zl + slot * NZ + 4 * c;
            const float4 z0 = *(const float4*)&zr[0];
            const float4 z1 = *(const float4*)&zr[104];
            const float4 z2 = *(const float4*)&zr[208];
            const float4 z3 = *(const float4*)&zr[312];
            const float4 z4 = *(const float4*)&zr[416];
            const float4 z5 = *(const float4*)&zr[520];
            const float4 z6 = *(const float4*)&zr[624];
            const float h0 = eA.x*z0.x + eA.y*z1.x + eA.z*z2.x + eA.w*z3.x
                           + eB.x*z4.x + eB.y*z5.x + eB.z*z6.x;
            const float h1 = eA.x*z0.y + eA.y*z1.y + eA.z*z2.y + eA.w*z3.y
                           + eB.x*z4.y + eB.y*z5.y + eB.z*z6.y;
            const float h2 = eA.x*z0.z + eA.y*z1.z + eA.z*z2.z + eA.w*z3.z
                           + eB.x*z4.z + eB.y*z5.z + eB.z*z6.z;
            const float h3 = eA.x*z0.w + eA.y*z1.w + eA.z*z2.w + eA.w*z3.w
                           + eB.x*z4.w + eB.y*z5.w + eB.z*z6.w;
            uint2 st;
            st.x = pk2(h0, h1);         // dword 2c   = comps (4c, 4c+1)
            st.y = pk2(h2, h3);         // dword 2c+1 = comps (4c+2, 4c+3)
            *(uint2*)&hbuf[(size_t)p * 52 + 2 * c] = st;
        }
        if (!more) break;
        qA = qA2; myq = myq2; slot = slot2; p = p2; eA = eA2; eB = eB2;
    }
}

// ---------------- K5: wave-per-node segment-sum (4-row pipelined) + fused V-contraction ----------------
// rtab row (64 fp32): [c0*r0[v] (7) | c1*r1[m*7+v] (21) | c2*r2[m*7+v] (35) | pad]

__global__ __launch_bounds__(256) void k_segsum(const unsigned int* __restrict__ hbuf,
                                                const float* __restrict__ shq,
                                                const int* __restrict__ offs_dst,
                                                const float* __restrict__ V1,
                                                const float* __restrict__ V2,
                                                const float* __restrict__ V3,
                                                float* __restrict__ rtab)
{
    __shared__ float ncl[4][224];       // per-wave n components (216 used)
    const int t = threadIdx.x, lane = t & 63, wid = t >> 6;
    const int node = blockIdx.x * 4 + wid;   // grid = 5000 exact
    const int beg = offs_dst[node], end = offs_dst[node + 1];

    float acc[10];
#pragma unroll
    for (int i = 0; i < 10; ++i) acc[i] = 0.f;
    const bool hasld = (lane < 52);

#define ACCUM(HD, SA, SB)                                                     \
    do {                                                                      \
        float va, vb;                                                         \
        unpk2(HD, va, vb);                                                    \
        if (lane < 32) {                                                      \
            acc[0] += va; acc[1] += vb;                                       \
        } else if (lane < 44) {                                               \
            acc[0] += va*(SA).x; acc[1] += va*(SA).y; acc[2] += va*(SA).z;    \
            acc[3] += vb*(SA).x; acc[4] += vb*(SA).y; acc[5] += vb*(SA).z;    \
        } else if (lane < 52) {                                               \
            acc[0] += va*(SA).w; acc[1] += va*(SB).x; acc[2] += va*(SB).y;    \
            acc[3] += va*(SB).z; acc[4] += va*(SB).w;                         \
            acc[5] += vb*(SA).w; acc[6] += vb*(SB).x; acc[7] += vb*(SB).y;    \
            acc[8] += vb*(SB).z; acc[9] += vb*(SB).w;                         \
        }                                                                     \
    } while (0)

    int r = beg;
    for (; r + 4 <= end; r += 4) {
        const unsigned int hd0 = hasld ? hbuf[(size_t)(r+0) * 52 + lane] : 0u;
        const unsigned int hd1 = hasld ? hbuf[(size_t)(r+1) * 52 + lane] : 0u;
        const unsigned int hd2 = hasld ? hbuf[(size_t)(r+2) * 52 + lane] : 0u;
        const unsigned int hd3 = hasld ? hbuf[(size_t)(r+3) * 52 + lane] : 0u;
        const float4 sA0 = *(const float4*)(shq + (size_t)(r+0) * 8);
        const float4 sB0 = *(const float4*)(shq + (size_t)(r+0) * 8 + 4);
        const float4 sA1 = *(const float4*)(shq + (size_t)(r+1) * 8);
        const float4 sB1 = *(const float4*)(shq + (size_t)(r+1) * 8 + 4);
        const float4 sA2 = *(const float4*)(shq + (size_t)(r+2) * 8);
        const float4 sB2 = *(const float4*)(shq + (size_t)(r+2) * 8 + 4);
        const float4 sA3 = *(const float4*)(shq + (size_t)(r+3) * 8);
        const float4 sB3 = *(const float4*)(shq + (size_t)(r+3) * 8 + 4);
        ACCUM(hd0, sA0, sB0);
        ACCUM(hd1, sA1, sB1);
        ACCUM(hd2, sA2, sB2);
        ACCUM(hd3, sA3, sB3);
    }
    for (; r < end; ++r) {
        const unsigned int hd = hasld ? hbuf[(size_t)r * 52 + lane] : 0u;
        const float4 sA = *(const float4*)(shq + (size_t)r * 8);
        const float4 sB = *(const float4*)(shq + (size_t)r * 8 + 4);
        ACCUM(hd, sA, sB);
    }
#undef ACCUM

    float* nw = ncl[wid];
    if (lane < 32) {
        nw[2*lane] = acc[0];
        nw[2*lane + 1] = acc[1];
    } else if (lane < 44) {
        const int wi = 2 * (lane - 32);
#pragma unroll
        for (int m = 0; m < 3; ++m) {
            nw[64 + wi*3 + m] = acc[m];
            nw[64 + (wi+1)*3 + m] = acc[3 + m];
        }
    } else if (lane < 52) {
        const int wi = 2 * (lane - 44);
#pragma unroll
        for (int m = 0; m < 5; ++m) {
            nw[136 + wi*5 + m] = acc[m];
            nw[136 + (wi+1)*5 + m] = acc[5 + m];
        }
    }
    __syncthreads();    // all waves reach exactly once

    float rv = 0.f;
    if (lane < 7) {
        const int v = lane;
#pragma unroll
        for (int u = 0; u < 64; ++u) rv += nw[u] * V1[u*7 + v];
        rv *= 0.04724556f;                    // 1/sqrt(64*7)
    } else if (lane < 28) {
        const int i = lane - 7, m = i / 7, v = i - 7*m;
#pragma unroll
        for (int u = 0; u < 24; ++u) rv += nw[64 + u*3 + m] * V2[u*7 + v];
        rv *= 0.04454354f;                    // 1/sqrt(24*7*3)
    } else if (lane < 63) {
        const int i = lane - 28, m = i / 7, v = i - 7*m;
#pragma unroll
        for (int u = 0; u < 16; ++u) rv += nw[136 + u*5 + m] * V3[u*7 + v];
        rv *= 0.04225771f;                    // 1/sqrt(16*7*5)
    }
    rtab[(size_t)node * 64 + lane] = rv;
}

// ---------------- K6: per-edge g via rtab; scatter to 16-way partial bins ----------------

__global__ __launch_bounds__(256) void k_gfinal(const float* __restrict__ pos,
                                                const float* __restrict__ eag,
                                                const int* __restrict__ esrc,
                                                const int* __restrict__ edst,
                                                const int* __restrict__ batch,
                                                const float* __restrict__ rtab,
                                                float* __restrict__ partial)
{
    const int e = blockIdx.x * 256 + threadIdx.x;   // grid = 1250 exact
    const int s = esrc[e], d = edst[e];
    float ea[7];
#pragma unroll
    for (int v = 0; v < 7; ++v) ea[v] = eag[(size_t)e * 7 + v];
    const float px = pos[3*s+0] - pos[3*d+0];
    const float py = pos[3*s+1] - pos[3*d+1];
    const float pz = pos[3*s+2] - pos[3*d+2];
    const float r2 = px*px + py*py + pz*pz;
    const float s10 = 1.7320508f*px, s11 = 1.7320508f*py, s12 = 1.7320508f*pz;
    const float s20 = 3.8729833f*px*py, s21 = 3.8729833f*py*pz,
                s22 = 1.1180340f*(3.f*pz*pz - r2), s23 = 3.8729833f*px*pz,
                s24 = 1.9364917f*(px*px - py*py);

    float rb[64];
    const float4* rr = (const float4*)(rtab + (size_t)s * 64);
#pragma unroll
    for (int i = 0; i < 16; ++i) *(float4*)&rb[4*i] = rr[i];

    float g = 0.f;
#pragma unroll
    for (int v = 0; v < 7; ++v) {
        const float tv = rb[v]
                       + s10*rb[7+v]  + s11*rb[14+v] + s12*rb[21+v]
                       + s20*rb[28+v] + s21*rb[35+v] + s22*rb[42+v]
                       + s23*rb[49+v] + s24*rb[56+v];
        g += ea[v] * tv;
    }
    unsafeAtomicAdd(&partial[(e & 15) * NG + batch[d]], g);
}

// ---------------- K7: reduce 16 partial rows -> out ----------------

__global__ __launch_bounds__(256) void k_reduce(const float* __restrict__ partial,
                                                float* __restrict__ out)
{
    const int gidx = threadIdx.x;
    float s = 0.f;
#pragma unroll
    for (int i = 0; i < 16; ++i) s += partial[i * NG + gidx];
    out[gidx] = s;
}

extern "C" void kernel_launch(void* const* d_in, const int* in_sizes, int n_in,
                              void* d_out, int out_size, void* d_ws, size_t ws_size,
                              hipStream_t stream)
{
    const float* pos  = (const float*)d_in[0];
    const float* x    = (const float*)d_in[1];
    const float* eag  = (const float*)d_in[2];
    const int*   eidx = (const int*)d_in[3];
    const int*   batch= (const int*)d_in[4];
    const float* W1   = (const float*)d_in[5];
    const float* W2   = (const float*)d_in[6];
    const float* W3   = (const float*)d_in[7];
    const float* V1   = (const float*)d_in[8];
    const float* V2   = (const float*)d_in[9];
    const float* V3   = (const float*)d_in[10];
    const int* esrc = eidx;
    const int* edst = eidx + NE;

    char* ws = (char*)d_ws;
    size_t off = 0;
    auto alloc = [&](size_t bytes) -> void* {
        void* p = ws + off;
        off = (off + bytes + 255) & ~(size_t)255;
        return p;
    };
    float* z        = (float*)alloc((size_t)NN * NZ * sizeof(float));        // 58.2 MB
    unsigned int* hbuf = (unsigned int*)alloc((size_t)NE * 52 * sizeof(unsigned int)); // 66.6 MB
    float* shq      = (float*)alloc((size_t)NE * 8 * sizeof(float));         // 10.2 MB
    float* eaq      = (float*)alloc((size_t)NE * 8 * sizeof(float));         // 10.2 MB
    float* rtab     = (float*)alloc((size_t)NN * 64 * sizeof(float));        // 5.1 MB
    int*   srcq     = (int*)alloc((size_t)NE * sizeof(int));
    int*   pq       = (int*)alloc((size_t)NE * sizeof(int));
    float* Wz       = (float*)alloc((size_t)24 * NZ * sizeof(float));
    int*   deg_src  = (int*)alloc((size_t)NN * sizeof(int));     // ---- zeroed region start
    int*   deg_dst  = (int*)alloc((size_t)NN * sizeof(int));
    float* partial  = (float*)alloc((size_t)16 * NG * sizeof(float));
    int*   offs_src = (int*)alloc((size_t)(NN + 1) * sizeof(int));  // ---- zeroed region end
    int*   offs_dst = (int*)alloc((size_t)(NN + 1) * sizeof(int));
    int*   cur_src  = (int*)alloc((size_t)NN * sizeof(int));
    int*   cur_dst  = (int*)alloc((size_t)NN * sizeof(int));

    hipMemsetAsync(deg_src, 0, (size_t)((char*)offs_src - (char*)deg_src), stream);

    k_count_wz<<<1250 + 69, 256, 0, stream>>>(esrc, edst, W1, W2, W3,
                                              deg_src, deg_dst, Wz);
    k_scan_nodez<<<2 + 2500, 256, 0, stream>>>(deg_src, deg_dst, x, Wz,
                                               offs_src, cur_src, offs_dst, cur_dst, z);
    k_fill<<<1250, 256, 0, stream>>>(pos, eag, esrc, edst, cur_src, cur_dst,
                                     srcq, pq, eaq, shq);
    k_edge_hb<<<NN/8, 256, 0, stream>>>(z, offs_src, srcq, pq, eaq, hbuf);
    k_segsum<<<NN/4, 256, 0, stream>>>(hbuf, shq, offs_dst, V1, V2, V3, rtab);
    k_gfinal<<<1250, 256, 0, stream>>>(pos, eag, esrc, edst, batch, rtab, partial);
    k_reduce<<<1, 256, 0, stream>>>(partial, (float*)d_out);
}

// Round 12
// 319.594 us; speedup vs baseline: 1.1784x; 1.0278x over previous
//
#include <hip/hip_runtime.h>

#define NN 20000
#define NE 320000
#define NG 256
#define NZ 728            // 7*104
#define NH 104            // 64+24+16
#define NCOMP 216         // 64 + 24*3 + 16*5

static __device__ __forceinline__ unsigned short f2bf(float f) {
    union { float f; unsigned int i; } c; c.f = f;
    unsigned int x = c.i;
    return (unsigned short)((x + 0x7FFFu + ((x >> 16) & 1u)) >> 16);
}
static __device__ __forceinline__ unsigned int pk2(float a, float b) {
    return ((unsigned int)f2bf(b) << 16) | (unsigned int)f2bf(a);
}
static __device__ __forceinline__ void unpk2(unsigned int w, float& a, float& b) {
    union { unsigned int i; float f; } c0, c1;
    c0.i = w << 16; c1.i = w & 0xFFFF0000u;
    a = c0.f; b = c1.f;
}

// ---------------- K1: blocks [0,1250) count degrees; rest build Wz (24 rows, row23=0) ----------------

__global__ __launch_bounds__(256) void k_count_wz(const int* __restrict__ esrc,
                                                  const int* __restrict__ edst,
                                                  const float* __restrict__ W1,
                                                  const float* __restrict__ W2,
                                                  const float* __restrict__ W3,
                                                  int* __restrict__ deg_src,
                                                  int* __restrict__ deg_dst,
                                                  float* __restrict__ Wz)
{
    const int b = blockIdx.x, t = threadIdx.x;
    if (b < 1250) {
        const int e = b * 256 + t;           // 1250*256 == NE exactly
        atomicAdd(&deg_src[esrc[e]], 1);
        atomicAdd(&deg_dst[edst[e]], 1);
    } else {
        const int idx = (b - 1250) * 256 + t;   // Wz: [u][v*104+w], a1 folded
        if (idx < 24 * NZ) {
            const int u = idx / NZ, c = idx - u * NZ;
            const int v = c / NH, w = c - v * NH;
            float val = 0.f;
            if (u < 23) {
                if (w < 64)      val = W1[(u*7 + v)*64 + w];
                else if (w < 88) val = W2[(u*7 + v)*24 + (w - 64)];
                else             val = W3[(u*7 + v)*16 + (w - 88)];
                val *= 0.07881104f;          // a1 = 1/sqrt(23*7)
            }
            Wz[idx] = val;
        }
    }
}

// ---------------- K2: blocks 0,1 scan degrees (shuffle scan); blocks 2.. node_z ----------------

__global__ __launch_bounds__(256) void k_scan_nodez(const int* __restrict__ deg_src,
                                                    const int* __restrict__ deg_dst,
                                                    const float* __restrict__ x,
                                                    const float* __restrict__ Wz,
                                                    int* __restrict__ offs_src,
                                                    int* __restrict__ cur_src,
                                                    int* __restrict__ offs_dst,
                                                    int* __restrict__ cur_dst,
                                                    float* __restrict__ z)
{
    __shared__ __align__(16) char smem[1024];
    const int b = blockIdx.x, t = threadIdx.x;
    if (b < 2) {
        int* wsum = (int*)smem;                 // [4]
        const int* deg = b ? deg_dst : deg_src;
        int* offs = b ? offs_dst : offs_src;
        int* cur  = b ? cur_dst  : cur_src;
        const int lane = t & 63, wid = t >> 6;
        const int NCH = 79;                     // 79*256 >= 20000
        int run = 0;
        int nextv = (t < NN) ? deg[t] : 0;
        for (int c = 0; c < NCH; ++c) {
            const int j = c * 256 + t;
            const int v = nextv;
            const int jn = j + 256;
            nextv = (c + 1 < NCH && jn < NN) ? deg[jn] : 0;   // prefetch
            int inc = v;
#pragma unroll
            for (int off = 1; off < 64; off <<= 1) {
                const int o = __shfl_up(inc, off, 64);
                if (lane >= off) inc += o;
            }
            if (lane == 63) wsum[wid] = inc;
            __syncthreads();
            int wbase = 0;
#pragma unroll
            for (int wv = 0; wv < 4; ++wv) if (wv < wid) wbase += wsum[wv];
            const int excl = run + wbase + inc - v;
            if (j < NN) { offs[j] = excl; cur[j] = excl; }
            run += wsum[0] + wsum[1] + wsum[2] + wsum[3];
            __syncthreads();
        }
        if (t == 255) offs[NN] = run;
    } else {
        float (*xa)[24] = (float (*)[24])smem;
        const int base = (b - 2) * 8;
        if (t < 192) {
            const int nl = t / 24, u = t - nl * 24;
            xa[nl][u] = (u < 23) ? x[(size_t)(base + nl) * 23 + u] : 0.f;
        }
        __syncthreads();
        const int c0 = t, c1 = t + 256, c2 = t + 512;
        const bool has2 = (c2 < NZ);
        float acc[8][3];
#pragma unroll
        for (int n = 0; n < 8; ++n) { acc[n][0] = 0.f; acc[n][1] = 0.f; acc[n][2] = 0.f; }
#pragma unroll
        for (int u4 = 0; u4 < 24; u4 += 4) {
            float w[4][3];
#pragma unroll
            for (int k = 0; k < 4; ++k) {
                const float* wr = Wz + (u4 + k) * NZ;
                w[k][0] = wr[c0];
                w[k][1] = wr[c1];
                w[k][2] = has2 ? wr[c2] : 0.f;
            }
#pragma unroll
            for (int n = 0; n < 8; ++n) {
                const float4 xv = *(const float4*)&xa[n][u4];
                acc[n][0] += xv.x*w[0][0] + xv.y*w[1][0] + xv.z*w[2][0] + xv.w*w[3][0];
                acc[n][1] += xv.x*w[0][1] + xv.y*w[1][1] + xv.z*w[2][1] + xv.w*w[3][1];
                acc[n][2] += xv.x*w[0][2] + xv.y*w[1][2] + xv.z*w[2][2] + xv.w*w[3][2];
            }
        }
#pragma unroll
        for (int n = 0; n < 8; ++n) {
            float* zo = z + (size_t)(base + n) * NZ;
            zo[c0] = acc[n][0];
            zo[c1] = acc[n][1];
            if (has2) zo[c2] = acc[n][2];
        }
    }
}

// ---------------- K3: fill dual CSR; pre-gather ea (stride 8) and sh (dst order) ----------------

__global__ __launch_bounds__(256) void k_fill(const float* __restrict__ pos,
                                              const float* __restrict__ eag,
                                              const int* __restrict__ esrc,
                                              const int* __restrict__ edst,
                                              int* __restrict__ cur_src,
                                              int* __restrict__ cur_dst,
                                              int* __restrict__ srcq,
                                              int* __restrict__ pq,
                                              float* __restrict__ eaq,
                                              float* __restrict__ shq)
{
    const int e = blockIdx.x * 256 + threadIdx.x;   // grid = 1250 exact
    const int s = esrc[e], d = edst[e];
    const int q = atomicAdd(&cur_src[s], 1);
    const int p = atomicAdd(&cur_dst[d], 1);
    srcq[q] = s;
    pq[q] = p;
    float* o = eaq + (size_t)q * 8;
#pragma unroll
    for (int v = 0; v < 7; ++v) o[v] = eag[(size_t)e * 7 + v];
    o[7] = 0.f;
    const float px = pos[3*s+0] - pos[3*d+0];
    const float py = pos[3*s+1] - pos[3*d+1];
    const float pz = pos[3*s+2] - pos[3*d+2];
    const float r2 = px*px + py*py + pz*pz;
    float* sh = shq + (size_t)p * 8;
    sh[0] = 1.7320508f*px;
    sh[1] = 1.7320508f*py;
    sh[2] = 1.7320508f*pz;
    sh[3] = 3.8729833f*px*py;
    sh[4] = 3.8729833f*py*pz;
    sh[5] = 1.1180340f*(3.f*pz*pz - r2);
    sh[6] = 3.8729833f*px*pz;
    sh[7] = 1.9364917f*(px*px - py*py);
}

// ---------------- K4: per-edge h; 4 nodes/block, half-wave edge pairing, b128 LDS reads ----------------
// Half-wave: lanes 0-31 = edge A, lanes 32-63 = edge B; lane c<26 computes comps 4c..4c+3
// via 7 ds_read_b128, stores uint2. hbuf dword d of a row = bf16 comps (2d, 2d+1).

__global__ __launch_bounds__(256) void k_edge_hb(const float* __restrict__ z,
                                                 const int* __restrict__ offs_src,
                                                 const int* __restrict__ srcq,
                                                 const int* __restrict__ pq,
                                                 const float* __restrict__ eaq,
                                                 unsigned int* __restrict__ hbuf)
{
    __shared__ float zl[4 * NZ];   // 11648 B
    const int t = threadIdx.x;
    const int base = blockIdx.x * 4;
    const float4* zg = (const float4*)(z + (size_t)base * NZ);
    float4* zl4 = (float4*)zl;
    for (int i = t; i < NZ; i += 256) zl4[i] = zg[i];   // 4*NZ/4 = NZ float4s
    const int qbeg = offs_src[base], qend = offs_src[base + 4];
    __syncthreads();

    const int lane = t & 63, wid = t >> 6;
    const int sub = lane >> 5;          // half-wave id (edge A/B)
    const int c = lane & 31;            // 0..31; active c < 26

    int qA = qbeg + 2 * wid;            // wave-uniform pair base, stride 8
    if (qA >= qend) return;
    int myq = qA + sub;
    int slot = 0, p = 0;
    float4 eA = make_float4(0.f,0.f,0.f,0.f), eB = eA;
    if (myq < qend) {
        slot = srcq[myq] - base;
        p = pq[myq];
        eA = ((const float4*)(eaq + (size_t)myq * 8))[0];
        eB = ((const float4*)(eaq + (size_t)myq * 8))[1];
    }

    while (1) {
        const int qA2 = qA + 8;
        const bool more = qA2 < qend;
        const int myq2 = qA2 + sub;
        int slot2 = 0, p2 = 0;
        float4 eA2 = eA, eB2 = eB;
        if (more && myq2 < qend) {
            slot2 = srcq[myq2] - base;
            p2 = pq[myq2];
            eA2 = ((const float4*)(eaq + (size_t)myq2 * 8))[0];
            eB2 = ((const float4*)(eaq + (size_t)myq2 * 8))[1];
        }
        if (myq < qend && c < 26) {
            const float* zr = zl + slot * NZ + 4 * c;
            const float4 z0 = *(const float4*)&zr[0];
            const float4 z1 = *(const float4*)&zr[104];
            const float4 z2 = *(const float4*)&zr[208];
            const float4 z3 = *(const float4*)&zr[312];
            const float4 z4 = *(const float4*)&zr[416];
            const float4 z5 = *(const float4*)&zr[520];
            const float4 z6 = *(const float4*)&zr[624];
            const float h0 = eA.x*z0.x + eA.y*z1.x + eA.z*z2.x + eA.w*z3.x
                           + eB.x*z4.x + eB.y*z5.x + eB.z*z6.x;
            const float h1 = eA.x*z0.y + eA.y*z1.y + eA.z*z2.y + eA.w*z3.y
                           + eB.x*z4.y + eB.y*z5.y + eB.z*z6.y;
            const float h2 = eA.x*z0.z + eA.y*z1.z + eA.z*z2.z + eA.w*z3.z
                           + eB.x*z4.z + eB.y*z5.z + eB.z*z6.z;
            const float h3 = eA.x*z0.w + eA.y*z1.w + eA.z*z2.w + eA.w*z3.w
                           + eB.x*z4.w + eB.y*z5.w + eB.z*z6.w;
            uint2 st;
            st.x = pk2(h0, h1);
            st.y = pk2(h2, h3);
            *(uint2*)&hbuf[(size_t)p * 52 + 2 * c] = st;
        }
        if (!more) break;
        qA = qA2; myq = myq2; slot = slot2; p = p2; eA = eA2; eB = eB2;
    }
}

// ---------------- K5: wave-per-node segment-sum (8-row pipelined) + fused V-contraction ----------------
// rtab row (64 fp32): [c0*r0[v] (7) | c1*r1[m*7+v] (21) | c2*r2[m*7+v] (35) | pad]

__global__ __launch_bounds__(256) void k_segsum(const unsigned int* __restrict__ hbuf,
                                                const float* __restrict__ shq,
                                                const int* __restrict__ offs_dst,
                                                const float* __restrict__ V1,
                                                const float* __restrict__ V2,
                                                const float* __restrict__ V3,
                                                float* __restrict__ rtab)
{
    __shared__ float ncl[4][224];       // per-wave n components (216 used)
    const int t = threadIdx.x, lane = t & 63, wid = t >> 6;
    const int node = blockIdx.x * 4 + wid;   // grid = 5000 exact
    const int beg = offs_dst[node], end = offs_dst[node + 1];

    float acc[10];
#pragma unroll
    for (int i = 0; i < 10; ++i) acc[i] = 0.f;
    const bool hasld = (lane < 52);

#define ACCUM(HD, SA, SB)                                                     \
    do {                                                                      \
        float va, vb;                                                         \
        unpk2(HD, va, vb);                                                    \
        if (lane < 32) {                                                      \
            acc[0] += va; acc[1] += vb;                                       \
        } else if (lane < 44) {                                               \
            acc[0] += va*(SA).x; acc[1] += va*(SA).y; acc[2] += va*(SA).z;    \
            acc[3] += vb*(SA).x; acc[4] += vb*(SA).y; acc[5] += vb*(SA).z;    \
        } else if (lane < 52) {                                               \
            acc[0] += va*(SA).w; acc[1] += va*(SB).x; acc[2] += va*(SB).y;    \
            acc[3] += va*(SB).z; acc[4] += va*(SB).w;                         \
            acc[5] += vb*(SA).w; acc[6] += vb*(SB).x; acc[7] += vb*(SB).y;    \
            acc[8] += vb*(SB).z; acc[9] += vb*(SB).w;                         \
        }                                                                     \
    } while (0)

    int r = beg;
    for (; r + 8 <= end; r += 8) {
        unsigned int hd[8];
        float4 sA[8], sB[8];
#pragma unroll
        for (int k = 0; k < 8; ++k)
            hd[k] = hasld ? hbuf[(size_t)(r+k) * 52 + lane] : 0u;
#pragma unroll
        for (int k = 0; k < 8; ++k) {
            sA[k] = *(const float4*)(shq + (size_t)(r+k) * 8);      // wave-uniform
            sB[k] = *(const float4*)(shq + (size_t)(r+k) * 8 + 4);
        }
#pragma unroll
        for (int k = 0; k < 8; ++k) ACCUM(hd[k], sA[k], sB[k]);
    }
    for (; r + 4 <= end; r += 4) {
        unsigned int hd[4];
        float4 sA[4], sB[4];
#pragma unroll
        for (int k = 0; k < 4; ++k)
            hd[k] = hasld ? hbuf[(size_t)(r+k) * 52 + lane] : 0u;
#pragma unroll
        for (int k = 0; k < 4; ++k) {
            sA[k] = *(const float4*)(shq + (size_t)(r+k) * 8);
            sB[k] = *(const float4*)(shq + (size_t)(r+k) * 8 + 4);
        }
#pragma unroll
        for (int k = 0; k < 4; ++k) ACCUM(hd[k], sA[k], sB[k]);
    }
    for (; r < end; ++r) {
        const unsigned int hd = hasld ? hbuf[(size_t)r * 52 + lane] : 0u;
        const float4 sA = *(const float4*)(shq + (size_t)r * 8);
        const float4 sB = *(const float4*)(shq + (size_t)r * 8 + 4);
        ACCUM(hd, sA, sB);
    }
#undef ACCUM

    float* nw = ncl[wid];
    if (lane < 32) {
        nw[2*lane] = acc[0];
        nw[2*lane + 1] = acc[1];
    } else if (lane < 44) {
        const int wi = 2 * (lane - 32);
#pragma unroll
        for (int m = 0; m < 3; ++m) {
            nw[64 + wi*3 + m] = acc[m];
            nw[64 + (wi+1)*3 + m] = acc[3 + m];
        }
    } else if (lane < 52) {
        const int wi = 2 * (lane - 44);
#pragma unroll
        for (int m = 0; m < 5; ++m) {
            nw[136 + wi*5 + m] = acc[m];
            nw[136 + (wi+1)*5 + m] = acc[5 + m];
        }
    }
    __syncthreads();    // all waves reach exactly once

    float rv = 0.f;
    if (lane < 7) {
        const int v = lane;
#pragma unroll
        for (int u = 0; u < 64; ++u) rv += nw[u] * V1[u*7 + v];
        rv *= 0.04724556f;                    // 1/sqrt(64*7)
    } else if (lane < 28) {
        const int i = lane - 7, m = i / 7, v = i - 7*m;
#pragma unroll
        for (int u = 0; u < 24; ++u) rv += nw[64 + u*3 + m] * V2[u*7 + v];
        rv *= 0.04454354f;                    // 1/sqrt(24*7*3)
    } else if (lane < 63) {
        const int i = lane - 28, m = i / 7, v = i - 7*m;
#pragma unroll
        for (int u = 0; u < 16; ++u) rv += nw[136 + u*5 + m] * V3[u*7 + v];
        rv *= 0.04225771f;                    // 1/sqrt(16*7*5)
    }
    rtab[(size_t)node * 64 + lane] = rv;
}

// ---------------- K6: per-edge g via rtab; scatter to 16-way partial bins ----------------

__global__ __launch_bounds__(256) void k_gfinal(const float* __restrict__ pos,
                                                const float* __restrict__ eag,
                                                const int* __restrict__ esrc,
                                                const int* __restrict__ edst,
                                                const int* __restrict__ batch,
                                                const float* __restrict__ rtab,
                                                float* __restrict__ partial)
{
    const int e = blockIdx.x * 256 + threadIdx.x;   // grid = 1250 exact
    const int s = esrc[e], d = edst[e];
    float ea[7];
#pragma unroll
    for (int v = 0; v < 7; ++v) ea[v] = eag[(size_t)e * 7 + v];
    const float px = pos[3*s+0] - pos[3*d+0];
    const float py = pos[3*s+1] - pos[3*d+1];
    const float pz = pos[3*s+2] - pos[3*d+2];
    const float r2 = px*px + py*py + pz*pz;
    const float s10 = 1.7320508f*px, s11 = 1.7320508f*py, s12 = 1.7320508f*pz;
    const float s20 = 3.8729833f*px*py, s21 = 3.8729833f*py*pz,
                s22 = 1.1180340f*(3.f*pz*pz - r2), s23 = 3.8729833f*px*pz,
                s24 = 1.9364917f*(px*px - py*py);

    float rb[64];
    const float4* rr = (const float4*)(rtab + (size_t)s * 64);
#pragma unroll
    for (int i = 0; i < 16; ++i) *(float4*)&rb[4*i] = rr[i];

    float g = 0.f;
#pragma unroll
    for (int v = 0; v < 7; ++v) {
        const float tv = rb[v]
                       + s10*rb[7+v]  + s11*rb[14+v] + s12*rb[21+v]
                       + s20*rb[28+v] + s21*rb[35+v] + s22*rb[42+v]
                       + s23*rb[49+v] + s24*rb[56+v];
        g += ea[v] * tv;
    }
    unsafeAtomicAdd(&partial[(e & 15) * NG + batch[d]], g);
}

// ---------------- K7: reduce 16 partial rows -> out ----------------

__global__ __launch_bounds__(256) void k_reduce(const float* __restrict__ partial,
                                                float* __restrict__ out)
{
    const int gidx = threadIdx.x;
    float s = 0.f;
#pragma unroll
    for (int i = 0; i < 16; ++i) s += partial[i * NG + gidx];
    out[gidx] = s;
}

extern "C" void kernel_launch(void* const* d_in, const int* in_sizes, int n_in,
                              void* d_out, int out_size, void* d_ws, size_t ws_size,
                              hipStream_t stream)
{
    const float* pos  = (const float*)d_in[0];
    const float* x    = (const float*)d_in[1];
    const float* eag  = (const float*)d_in[2];
    const int*   eidx = (const int*)d_in[3];
    const int*   batch= (const int*)d_in[4];
    const float* W1   = (const float*)d_in[5];
    const float* W2   = (const float*)d_in[6];
    const float* W3   = (const float*)d_in[7];
    const float* V1   = (const float*)d_in[8];
    const float* V2   = (const float*)d_in[9];
    const float* V3   = (const float*)d_in[10];
    const int* esrc = eidx;
    const int* edst = eidx + NE;

    char* ws = (char*)d_ws;
    size_t off = 0;
    auto alloc = [&](size_t bytes) -> void* {
        void* p = ws + off;
        off = (off + bytes + 255) & ~(size_t)255;
        return p;
    };
    float* z        = (float*)alloc((size_t)NN * NZ * sizeof(float));        // 58.2 MB
    unsigned int* hbuf = (unsigned int*)alloc((size_t)NE * 52 * sizeof(unsigned int)); // 66.6 MB
    float* shq      = (float*)alloc((size_t)NE * 8 * sizeof(float));         // 10.2 MB
    float* eaq      = (float*)alloc((size_t)NE * 8 * sizeof(float));         // 10.2 MB
    float* rtab     = (float*)alloc((size_t)NN * 64 * sizeof(float));        // 5.1 MB
    int*   srcq     = (int*)alloc((size_t)NE * sizeof(int));
    int*   pq       = (int*)alloc((size_t)NE * sizeof(int));
    float* Wz       = (float*)alloc((size_t)24 * NZ * sizeof(float));
    int*   deg_src  = (int*)alloc((size_t)NN * sizeof(int));     // ---- zeroed region start
    int*   deg_dst  = (int*)alloc((size_t)NN * sizeof(int));
    float* partial  = (float*)alloc((size_t)16 * NG * sizeof(float));
    int*   offs_src = (int*)alloc((size_t)(NN + 1) * sizeof(int));  // ---- zeroed region end
    int*   offs_dst = (int*)alloc((size_t)(NN + 1) * sizeof(int));
    int*   cur_src  = (int*)alloc((size_t)NN * sizeof(int));
    int*   cur_dst  = (int*)alloc((size_t)NN * sizeof(int));

    hipMemsetAsync(deg_src, 0, (size_t)((char*)offs_src - (char*)deg_src), stream);

    k_count_wz<<<1250 + 69, 256, 0, stream>>>(esrc, edst, W1, W2, W3,
                                              deg_src, deg_dst, Wz);
    k_scan_nodez<<<2 + 2500, 256, 0, stream>>>(deg_src, deg_dst, x, Wz,
                                               offs_src, cur_src, offs_dst, cur_dst, z);
    k_fill<<<1250, 256, 0, stream>>>(pos, eag, esrc, edst, cur_src, cur_dst,
                                     srcq, pq, eaq, shq);
    k_edge_hb<<<NN/4, 256, 0, stream>>>(z, offs_src, srcq, pq, eaq, hbuf);
    k_segsum<<<NN/4, 256, 0, stream>>>(hbuf, shq, offs_dst, V1, V2, V3, rtab);
    k_gfinal<<<1250, 256, 0, stream>>>(pos, eag, esrc, edst, batch, rtab, partial);
    k_reduce<<<1, 256, 0, stream>>>(partial, (float*)d_out);
}

// Round 14
// 311.619 us; speedup vs baseline: 1.2086x; 1.0256x over previous
//
#include <hip/hip_runtime.h>

#define NN 20000
#define NE 320000
#define NG 256
#define NZ 728            // 7*104
#define NH 104            // 64+24+16
#define NCOMP 216         // 64 + 24*3 + 16*5

static __device__ __forceinline__ unsigned short f2bf(float f) {
    union { float f; unsigned int i; } c; c.f = f;
    unsigned int x = c.i;
    return (unsigned short)((x + 0x7FFFu + ((x >> 16) & 1u)) >> 16);
}
static __device__ __forceinline__ unsigned int pk2(float a, float b) {
    return ((unsigned int)f2bf(b) << 16) | (unsigned int)f2bf(a);
}
static __device__ __forceinline__ void unpk2(unsigned int w, float& a, float& b) {
    union { unsigned int i; float f; } c0, c1;
    c0.i = w << 16; c1.i = w & 0xFFFF0000u;
    a = c0.f; b = c1.f;
}

// ---------------- K1: blocks [0,1250) count degrees; rest build Wz (24 rows, row23=0) ----------------

__global__ __launch_bounds__(256) void k_count_wz(const int* __restrict__ esrc,
                                                  const int* __restrict__ edst,
                                                  const float* __restrict__ W1,
                                                  const float* __restrict__ W2,
                                                  const float* __restrict__ W3,
                                                  int* __restrict__ deg_src,
                                                  int* __restrict__ deg_dst,
                                                  float* __restrict__ Wz)
{
    const int b = blockIdx.x, t = threadIdx.x;
    if (b < 1250) {
        const int e = b * 256 + t;           // 1250*256 == NE exactly
        atomicAdd(&deg_src[esrc[e]], 1);
        atomicAdd(&deg_dst[edst[e]], 1);
    } else {
        const int idx = (b - 1250) * 256 + t;   // Wz: [u][v*104+w], a1 folded
        if (idx < 24 * NZ) {
            const int u = idx / NZ, c = idx - u * NZ;
            const int v = c / NH, w = c - v * NH;
            float val = 0.f;
            if (u < 23) {
                if (w < 64)      val = W1[(u*7 + v)*64 + w];
                else if (w < 88) val = W2[(u*7 + v)*24 + (w - 64)];
                else             val = W3[(u*7 + v)*16 + (w - 88)];
                val *= 0.07881104f;          // a1 = 1/sqrt(23*7)
            }
            Wz[idx] = val;
        }
    }
}

// ---------------- K2: blocks 0,1 scan degrees (shuffle scan); blocks 2.. node_z ----------------

__global__ __launch_bounds__(256) void k_scan_nodez(const int* __restrict__ deg_src,
                                                    const int* __restrict__ deg_dst,
                                                    const float* __restrict__ x,
                                                    const float* __restrict__ Wz,
                                                    int* __restrict__ offs_src,
                                                    int* __restrict__ cur_src,
                                                    int* __restrict__ offs_dst,
                                                    int* __restrict__ cur_dst,
                                                    float* __restrict__ z)
{
    __shared__ __align__(16) char smem[1024];
    const int b = blockIdx.x, t = threadIdx.x;
    if (b < 2) {
        int* wsum = (int*)smem;                 // [4]
        const int* deg = b ? deg_dst : deg_src;
        int* offs = b ? offs_dst : offs_src;
        int* cur  = b ? cur_dst  : cur_src;
        const int lane = t & 63, wid = t >> 6;
        const int NCH = 79;                     // 79*256 >= 20000
        int run = 0;
        int nextv = (t < NN) ? deg[t] : 0;
        for (int c = 0; c < NCH; ++c) {
            const int j = c * 256 + t;
            const int v = nextv;
            const int jn = j + 256;
            nextv = (c + 1 < NCH && jn < NN) ? deg[jn] : 0;   // prefetch
            int inc = v;
#pragma unroll
            for (int off = 1; off < 64; off <<= 1) {
                const int o = __shfl_up(inc, off, 64);
                if (lane >= off) inc += o;
            }
            if (lane == 63) wsum[wid] = inc;
            __syncthreads();
            int wbase = 0;
#pragma unroll
            for (int wv = 0; wv < 4; ++wv) if (wv < wid) wbase += wsum[wv];
            const int excl = run + wbase + inc - v;
            if (j < NN) { offs[j] = excl; cur[j] = excl; }
            run += wsum[0] + wsum[1] + wsum[2] + wsum[3];
            __syncthreads();
        }
        if (t == 255) offs[NN] = run;
    } else {
        float (*xa)[24] = (float (*)[24])smem;
        const int base = (b - 2) * 8;
        if (t < 192) {
            const int nl = t / 24, u = t - nl * 24;
            xa[nl][u] = (u < 23) ? x[(size_t)(base + nl) * 23 + u] : 0.f;
        }
        __syncthreads();
        const int c0 = t, c1 = t + 256, c2 = t + 512;
        const bool has2 = (c2 < NZ);
        float acc[8][3];
#pragma unroll
        for (int n = 0; n < 8; ++n) { acc[n][0] = 0.f; acc[n][1] = 0.f; acc[n][2] = 0.f; }
#pragma unroll
        for (int u4 = 0; u4 < 24; u4 += 4) {
            float w[4][3];
#pragma unroll
            for (int k = 0; k < 4; ++k) {
                const float* wr = Wz + (u4 + k) * NZ;
                w[k][0] = wr[c0];
                w[k][1] = wr[c1];
                w[k][2] = has2 ? wr[c2] : 0.f;
            }
#pragma unroll
            for (int n = 0; n < 8; ++n) {
                const float4 xv = *(const float4*)&xa[n][u4];
                acc[n][0] += xv.x*w[0][0] + xv.y*w[1][0] + xv.z*w[2][0] + xv.w*w[3][0];
                acc[n][1] += xv.x*w[0][1] + xv.y*w[1][1] + xv.z*w[2][1] + xv.w*w[3][1];
                acc[n][2] += xv.x*w[0][2] + xv.y*w[1][2] + xv.z*w[2][2] + xv.w*w[3][2];
            }
        }
#pragma unroll
        for (int n = 0; n < 8; ++n) {
            float* zo = z + (size_t)(base + n) * NZ;
            zo[c0] = acc[n][0];
            zo[c1] = acc[n][1];
            if (has2) zo[c2] = acc[n][2];
        }
    }
}

// ---------------- K3: fill dual CSR; pre-gather ea (stride 8) and sh (dst order) ----------------

__global__ __launch_bounds__(256) void k_fill(const float* __restrict__ pos,
                                              const float* __restrict__ eag,
                                              const int* __restrict__ esrc,
                                              const int* __restrict__ edst,
                                              int* __restrict__ cur_src,
                                              int* __restrict__ cur_dst,
                                              int* __restrict__ srcq,
                                              int* __restrict__ pq,
                                              float* __restrict__ eaq,
                                              float* __restrict__ shq)
{
    const int e = blockIdx.x * 256 + threadIdx.x;   // grid = 1250 exact
    const int s = esrc[e], d = edst[e];
    const int q = atomicAdd(&cur_src[s], 1);
    const int p = atomicAdd(&cur_dst[d], 1);
    srcq[q] = s;
    pq[q] = p;
    float* o = eaq + (size_t)q * 8;
#pragma unroll
    for (int v = 0; v < 7; ++v) o[v] = eag[(size_t)e * 7 + v];
    o[7] = 0.f;
    const float px = pos[3*s+0] - pos[3*d+0];
    const float py = pos[3*s+1] - pos[3*d+1];
    const float pz = pos[3*s+2] - pos[3*d+2];
    const float r2 = px*px + py*py + pz*pz;
    float* sh = shq + (size_t)p * 8;
    sh[0] = 1.7320508f*px;
    sh[1] = 1.7320508f*py;
    sh[2] = 1.7320508f*pz;
    sh[3] = 3.8729833f*px*py;
    sh[4] = 3.8729833f*py*pz;
    sh[5] = 1.1180340f*(3.f*pz*pz - r2);
    sh[6] = 3.8729833f*px*pz;
    sh[7] = 1.9364917f*(px*px - py*py);
}

// ---------------- K4: per-edge h; 4 nodes/block, half-wave edge pairing, b128 LDS reads ----------------

__global__ __launch_bounds__(256) void k_edge_hb(const float* __restrict__ z,
                                                 const int* __restrict__ offs_src,
                                                 const int* __restrict__ srcq,
                                                 const int* __restrict__ pq,
                                                 const float* __restrict__ eaq,
                                                 unsigned int* __restrict__ hbuf)
{
    __shared__ float zl[4 * NZ];   // 11648 B
    const int t = threadIdx.x;
    const int base = blockIdx.x * 4;
    const float4* zg = (const float4*)(z + (size_t)base * NZ);
    float4* zl4 = (float4*)zl;
    for (int i = t; i < NZ; i += 256) zl4[i] = zg[i];
    const int qbeg = offs_src[base], qend = offs_src[base + 4];
    __syncthreads();

    const int lane = t & 63, wid = t >> 6;
    const int sub = lane >> 5;
    const int c = lane & 31;

    int qA = qbeg + 2 * wid;
    if (qA >= qend) return;
    int myq = qA + sub;
    int slot = 0, p = 0;
    float4 eA = make_float4(0.f,0.f,0.f,0.f), eB = eA;
    if (myq < qend) {
        slot = srcq[myq] - base;
        p = pq[myq];
        eA = ((const float4*)(eaq + (size_t)myq * 8))[0];
        eB = ((const float4*)(eaq + (size_t)myq * 8))[1];
    }

    while (1) {
        const int qA2 = qA + 8;
        const bool more = qA2 < qend;
        const int myq2 = qA2 + sub;
        int slot2 = 0, p2 = 0;
        float4 eA2 = eA, eB2 = eB;
        if (more && myq2 < qend) {
            slot2 = srcq[myq2] - base;
            p2 = pq[myq2];
            eA2 = ((const float4*)(eaq + (size_t)myq2 * 8))[0];
            eB2 = ((const float4*)(eaq + (size_t)myq2 * 8))[1];
        }
        if (myq < qend && c < 26) {
            const float* zr = zl + slot * NZ + 4 * c;
            const float4 z0 = *(const float4*)&zr[0];
            const float4 z1 = *(const float4*)&zr[104];
            const float4 z2 = *(const float4*)&zr[208];
            const float4 z3 = *(const float4*)&zr[312];
            const float4 z4 = *(const float4*)&zr[416];
            const float4 z5 = *(const float4*)&zr[520];
            const float4 z6 = *(const float4*)&zr[624];
            const float h0 = eA.x*z0.x + eA.y*z1.x + eA.z*z2.x + eA.w*z3.x
                           + eB.x*z4.x + eB.y*z5.x + eB.z*z6.x;
            const float h1 = eA.x*z0.y + eA.y*z1.y + eA.z*z2.y + eA.w*z3.y
                           + eB.x*z4.y + eB.y*z5.y + eB.z*z6.y;
            const float h2 = eA.x*z0.z + eA.y*z1.z + eA.z*z2.z + eA.w*z3.z
                           + eB.x*z4.z + eB.y*z5.z + eB.z*z6.z;
            const float h3 = eA.x*z0.w + eA.y*z1.w + eA.z*z2.w + eA.w*z3.w
                           + eB.x*z4.w + eB.y*z5.w + eB.z*z6.w;
            uint2 st;
            st.x = pk2(h0, h1);
            st.y = pk2(h2, h3);
            *(uint2*)&hbuf[(size_t)p * 52 + 2 * c] = st;
        }
        if (!more) break;
        qA = qA2; myq = myq2; slot = slot2; p = p2; eA = eA2; eB = eB2;
    }
}

// ---------------- K5: wave-per-node segment-sum (8-row pipelined) + fused V-contraction ----------------
// rtab row (64 fp32): [c0*r0[v] (7) | c1*r1[m*7+v] (21) | c2*r2[m*7+v] (35) | pad]

__global__ __launch_bounds__(256) void k_segsum(const unsigned int* __restrict__ hbuf,
                                                const float* __restrict__ shq,
                                                const int* __restrict__ offs_dst,
                                                const float* __restrict__ V1,
                                                const float* __restrict__ V2,
                                                const float* __restrict__ V3,
                                                float* __restrict__ rtab)
{
    __shared__ float ncl[4][224];
    const int t = threadIdx.x, lane = t & 63, wid = t >> 6;
    const int node = blockIdx.x * 4 + wid;
    const int beg = offs_dst[node], end = offs_dst[node + 1];

    float acc[10];
#pragma unroll
    for (int i = 0; i < 10; ++i) acc[i] = 0.f;
    const bool hasld = (lane < 52);

#define ACCUM(HD, SA, SB)                                                     \
    do {                                                                      \
        float va, vb;                                                         \
        unpk2(HD, va, vb);                                                    \
        if (lane < 32) {                                                      \
            acc[0] += va; acc[1] += vb;                                       \
        } else if (lane < 44) {                                               \
            acc[0] += va*(SA).x; acc[1] += va*(SA).y; acc[2] += va*(SA).z;    \
            acc[3] += vb*(SA).x; acc[4] += vb*(SA).y; acc[5] += vb*(SA).z;    \
        } else if (lane < 52) {                                               \
            acc[0] += va*(SA).w; acc[1] += va*(SB).x; acc[2] += va*(SB).y;    \
            acc[3] += va*(SB).z; acc[4] += va*(SB).w;                         \
            acc[5] += vb*(SA).w; acc[6] += vb*(SB).x; acc[7] += vb*(SB).y;    \
            acc[8] += vb*(SB).z; acc[9] += vb*(SB).w;                         \
        }                                                                     \
    } while (0)

    int r = beg;
    for (; r + 8 <= end; r += 8) {
        unsigned int hd[8];
        float4 sA[8], sB[8];
#pragma unroll
        for (int k = 0; k < 8; ++k)
            hd[k] = hasld ? hbuf[(size_t)(r+k) * 52 + lane] : 0u;
#pragma unroll
        for (int k = 0; k < 8; ++k) {
            sA[k] = *(const float4*)(shq + (size_t)(r+k) * 8);
            sB[k] = *(const float4*)(shq + (size_t)(r+k) * 8 + 4);
        }
#pragma unroll
        for (int k = 0; k < 8; ++k) ACCUM(hd[k], sA[k], sB[k]);
    }
    for (; r + 4 <= end; r += 4) {
        unsigned int hd[4];
        float4 sA[4], sB[4];
#pragma unroll
        for (int k = 0; k < 4; ++k)
            hd[k] = hasld ? hbuf[(size_t)(r+k) * 52 + lane] : 0u;
#pragma unroll
        for (int k = 0; k < 4; ++k) {
            sA[k] = *(const float4*)(shq + (size_t)(r+k) * 8);
            sB[k] = *(const float4*)(shq + (size_t)(r+k) * 8 + 4);
        }
#pragma unroll
        for (int k = 0; k < 4; ++k) ACCUM(hd[k], sA[k], sB[k]);
    }
    for (; r < end; ++r) {
        const unsigned int hd = hasld ? hbuf[(size_t)r * 52 + lane] : 0u;
        const float4 sA = *(const float4*)(shq + (size_t)r * 8);
        const float4 sB = *(const float4*)(shq + (size_t)r * 8 + 4);
        ACCUM(hd, sA, sB);
    }
#undef ACCUM

    float* nw = ncl[wid];
    if (lane < 32) {
        nw[2*lane] = acc[0];
        nw[2*lane + 1] = acc[1];
    } else if (lane < 44) {
        const int wi = 2 * (lane - 32);
#pragma unroll
        for (int m = 0; m < 3; ++m) {
            nw[64 + wi*3 + m] = acc[m];
            nw[64 + (wi+1)*3 + m] = acc[3 + m];
        }
    } else if (lane < 52) {
        const int wi = 2 * (lane - 44);
#pragma unroll
        for (int m = 0; m < 5; ++m) {
            nw[136 + wi*5 + m] = acc[m];
            nw[136 + (wi+1)*5 + m] = acc[5 + m];
        }
    }
    __syncthreads();

    float rv = 0.f;
    if (lane < 7) {
        const int v = lane;
#pragma unroll
        for (int u = 0; u < 64; ++u) rv += nw[u] * V1[u*7 + v];
        rv *= 0.04724556f;
    } else if (lane < 28) {
        const int i = lane - 7, m = i / 7, v = i - 7*m;
#pragma unroll
        for (int u = 0; u < 24; ++u) rv += nw[64 + u*3 + m] * V2[u*7 + v];
        rv *= 0.04454354f;
    } else if (lane < 63) {
        const int i = lane - 28, m = i / 7, v = i - 7*m;
#pragma unroll
        for (int u = 0; u < 16; ++u) rv += nw[136 + u*5 + m] * V3[u*7 + v];
        rv *= 0.04225771f;
    }
    rtab[(size_t)node * 64 + lane] = rv;
}

// ---------------- K6: per-edge g via rtab -> LDS graph bins -> out (fused final+reduce) ----------------

__global__ __launch_bounds__(256) void k_gfinal(const float* __restrict__ pos,
                                                const float* __restrict__ eag,
                                                const int* __restrict__ esrc,
                                                const int* __restrict__ edst,
                                                const int* __restrict__ batch,
                                                const float* __restrict__ rtab,
                                                float* __restrict__ out)
{
    __shared__ float bins[NG];
    const int t = threadIdx.x;
    bins[t] = 0.f;
    __syncthreads();

    const int e0 = blockIdx.x * 1024;
    for (int it = 0; it < 4; ++it) {
        const int e = e0 + it * 256 + t;
        if (e < NE) {
            const int s = esrc[e], d = edst[e];
            float ea[7];
#pragma unroll
            for (int v = 0; v < 7; ++v) ea[v] = eag[(size_t)e * 7 + v];
            const float px = pos[3*s+0] - pos[3*d+0];
            const float py = pos[3*s+1] - pos[3*d+1];
            const float pz = pos[3*s+2] - pos[3*d+2];
            const float r2 = px*px + py*py + pz*pz;
            const float s10 = 1.7320508f*px, s11 = 1.7320508f*py, s12 = 1.7320508f*pz;
            const float s20 = 3.8729833f*px*py, s21 = 3.8729833f*py*pz,
                        s22 = 1.1180340f*(3.f*pz*pz - r2), s23 = 3.8729833f*px*pz,
                        s24 = 1.9364917f*(px*px - py*py);

            float rb[64];
            const float4* rr = (const float4*)(rtab + (size_t)s * 64);
#pragma unroll
            for (int i = 0; i < 16; ++i) *(float4*)&rb[4*i] = rr[i];

            float g = 0.f;
#pragma unroll
            for (int v = 0; v < 7; ++v) {
                const float tv = rb[v]
                               + s10*rb[7+v]  + s11*rb[14+v] + s12*rb[21+v]
                               + s20*rb[28+v] + s21*rb[35+v] + s22*rb[42+v]
                               + s23*rb[49+v] + s24*rb[56+v];
                g += ea[v] * tv;
            }
            atomicAdd(&bins[batch[d]], g);   // LDS atomic (ds_add_f32)
        }
    }
    __syncthreads();
    unsafeAtomicAdd(&out[t], bins[t]);
}

extern "C" void kernel_launch(void* const* d_in, const int* in_sizes, int n_in,
                              void* d_out, int out_size, void* d_ws, size_t ws_size,
                              hipStream_t stream)
{
    const float* pos  = (const float*)d_in[0];
    const float* x    = (const float*)d_in[1];
    const float* eag  = (const float*)d_in[2];
    const int*   eidx = (const int*)d_in[3];
    const int*   batch= (const int*)d_in[4];
    const float* W1   = (const float*)d_in[5];
    const float* W2   = (const float*)d_in[6];
    const float* W3   = (const float*)d_in[7];
    const float* V1   = (const float*)d_in[8];
    const float* V2   = (const float*)d_in[9];
    const float* V3   = (const float*)d_in[10];
    const int* esrc = eidx;
    const int* edst = eidx + NE;

    char* ws = (char*)d_ws;
    size_t off = 0;
    auto alloc = [&](size_t bytes) -> void* {
        void* p = ws + off;
        off = (off + bytes + 255) & ~(size_t)255;
        return p;
    };
    float* z        = (float*)alloc((size_t)NN * NZ * sizeof(float));        // 58.2 MB
    unsigned int* hbuf = (unsigned int*)alloc((size_t)NE * 52 * sizeof(unsigned int)); // 66.6 MB
    float* shq      = (float*)alloc((size_t)NE * 8 * sizeof(float));         // 10.2 MB
    float* eaq      = (float*)alloc((size_t)NE * 8 * sizeof(float));         // 10.2 MB
    float* rtab     = (float*)alloc((size_t)NN * 64 * sizeof(float));        // 5.1 MB
    int*   srcq     = (int*)alloc((size_t)NE * sizeof(int));
    int*   pq       = (int*)alloc((size_t)NE * sizeof(int));
    float* Wz       = (float*)alloc((size_t)24 * NZ * sizeof(float));
    int*   deg_src  = (int*)alloc((size_t)NN * sizeof(int));     // ---- zeroed region start
    int*   deg_dst  = (int*)alloc((size_t)NN * sizeof(int));     // ---- zeroed region end
    int*   offs_src = (int*)alloc((size_t)(NN + 1) * sizeof(int));
    int*   offs_dst = (int*)alloc((size_t)(NN + 1) * sizeof(int));
    int*   cur_src  = (int*)alloc((size_t)NN * sizeof(int));
    int*   cur_dst  = (int*)alloc((size_t)NN * sizeof(int));

    hipMemsetAsync(deg_src, 0, (size_t)((char*)offs_src - (char*)deg_src), stream);
    hipMemsetAsync(d_out, 0, (size_t)NG * sizeof(float), stream);

    k_count_wz<<<1250 + 69, 256, 0, stream>>>(esrc, edst, W1, W2, W3,
                                              deg_src, deg_dst, Wz);
    k_scan_nodez<<<2 + 2500, 256, 0, stream>>>(deg_src, deg_dst, x, Wz,
                                               offs_src, cur_src, offs_dst, cur_dst, z);
    k_fill<<<1250, 256, 0, stream>>>(pos, eag, esrc, edst, cur_src, cur_dst,
                                     srcq, pq, eaq, shq);
    k_edge_hb<<<NN/4, 256, 0, stream>>>(z, offs_src, srcq, pq, eaq, hbuf);
    k_segsum<<<NN/4, 256, 0, stream>>>(hbuf, shq, offs_dst, V1, V2, V3, rtab);
    k_gfinal<<<(NE + 1023)/1024, 256, 0, stream>>>(pos, eag, esrc, edst, batch,
                                                   rtab, (float*)d_out);
}

// Round 15
// 220.110 us; speedup vs baseline: 1.7110x; 1.4157x over previous
//
#include <hip/hip_runtime.h>

#define NN 20000
#define NE 320000
#define NG 256
#define CAP 64            // dst bucket capacity; deg ~ Poisson(16), P(>64) ~ 1e-20
#define ZS 148            // Ztab row stride (147 used)

// edat row (16 floats = 64 B): [ea(7) | src(int) | sh1(3) | sh2(5)]

// ---------------- K1: blocks <1250 fill dst buckets; rest build WV ----------------
// WV[u][c], c = v'*21 + g*7 + v : a1*c_g * sum_w W_g[u,v',w] * V_g[w,v]

__global__ __launch_bounds__(256) void k_fill_wv(
    const float* __restrict__ pos,
    const float* __restrict__ eag,
    const int* __restrict__ esrc,
    const int* __restrict__ edst,
    const float* __restrict__ W1,
    const float* __restrict__ W2,
    const float* __restrict__ W3,
    const float* __restrict__ V1,
    const float* __restrict__ V2,
    const float* __restrict__ V3,
    int* __restrict__ deg,
    float* __restrict__ edat,
    float* __restrict__ WV)
{
    const int b = blockIdx.x, t = threadIdx.x;
    if (b < 1250) {
        const int e = b * 256 + t;          // 1250*256 == NE
        const int s = esrc[e], d = edst[e];
        const int slot = atomicAdd(&deg[d], 1);
        if (slot < CAP) {
            const int p = d * CAP + slot;
            float* o = edat + (size_t)p * 16;
#pragma unroll
            for (int v = 0; v < 7; ++v) o[v] = eag[(size_t)e * 7 + v];
            ((int*)o)[7] = s;
            const float px = pos[3*s+0] - pos[3*d+0];
            const float py = pos[3*s+1] - pos[3*d+1];
            const float pz = pos[3*s+2] - pos[3*d+2];
            const float r2 = px*px + py*py + pz*pz;
            o[8]  = 1.7320508f*px;
            o[9]  = 1.7320508f*py;
            o[10] = 1.7320508f*pz;
            o[11] = 3.8729833f*px*py;
            o[12] = 3.8729833f*py*pz;
            o[13] = 1.1180340f*(3.f*pz*pz - r2);
            o[14] = 3.8729833f*px*pz;
            o[15] = 1.9364917f*(px*px - py*py);
        }
    } else {
        const int idx = (b - 1250) * 256 + t;
        if (idx < 23 * 147) {
            const int u = idx / 147, c = idx - u * 147;
            const int vp = c / 21, col = c - vp * 21;
            const int g = col / 7, v = col - g * 7;
            float sum = 0.f;
            if (g == 0) {
                for (int w = 0; w < 64; ++w)
                    sum += W1[(u*7 + vp)*64 + w] * V1[w*7 + v];
                sum *= 0.07881104f * 0.04724556f;   // a1 * 1/sqrt(64*7)
            } else if (g == 1) {
                for (int w = 0; w < 24; ++w)
                    sum += W2[(u*7 + vp)*24 + w] * V2[w*7 + v];
                sum *= 0.07881104f * 0.04454354f;   // a1 * 1/sqrt(24*7*3)
            } else {
                for (int w = 0; w < 16; ++w)
                    sum += W3[(u*7 + vp)*16 + w] * V3[w*7 + v];
                sum *= 0.07881104f * 0.04225771f;   // a1 * 1/sqrt(16*7*5)
            }
            WV[idx] = sum;                           // [u][147] row-major
        }
    }
}

// ---------------- K2: Ztab[n][c] = sum_u x[n][u] * WV[u][c]  (8 nodes/block) ----------------

__global__ __launch_bounds__(256) void k_ztab(const float* __restrict__ x,
                                              const float* __restrict__ WV,
                                              float* __restrict__ Ztab)
{
    __shared__ float xa[8][23];
    const int b = blockIdx.x, t = threadIdx.x;   // grid 2500 exact
    const int base = b * 8;
    if (t < 184) {
        const int nl = t / 23, u = t - nl * 23;
        xa[nl][u] = x[(size_t)(base + nl) * 23 + u];
    }
    __syncthreads();
    if (t < 147) {
        float acc[8];
#pragma unroll
        for (int n = 0; n < 8; ++n) acc[n] = 0.f;
        for (int u = 0; u < 23; ++u) {
            const float wv = WV[u * 147 + t];     // coalesced
#pragma unroll
            for (int n = 0; n < 8; ++n) acc[n] += xa[n][u] * wv;
        }
#pragma unroll
        for (int n = 0; n < 8; ++n)
            Ztab[(size_t)(base + n) * ZS + t] = acc[n];
    }
}

// ---------------- K3: wave per dst node; acc[lane] = rtab comp; fp32 throughout ----------------
// rtab row (64 fp32): [r0[v](7) | r1[m,v] m-major (21) | r2[m,v] m-major (35) | pad]

__global__ __launch_bounds__(256) void k_edge_acc(const float* __restrict__ Ztab,
                                                  const int* __restrict__ deg,
                                                  const float* __restrict__ edat,
                                                  float* __restrict__ rtab)
{
    const int t = threadIdx.x, lane = t & 63;
    const int node = __builtin_amdgcn_readfirstlane(blockIdx.x * 4 + (t >> 6));
    const int dg = min(deg[node], CAP);
    const int pb = node * CAP;

    // per-lane constants
    int col, sidx; bool unit;
    if (lane < 7)       { col = lane;        sidx = 0;              unit = true;  }
    else if (lane < 28) { const int i = lane - 7;  col = 7  + i % 7; sidx = i / 7;     unit = false; }
    else if (lane < 63) { const int i = lane - 28; col = 14 + i % 7; sidx = 3 + i / 7; unit = false; }
    else                { col = 0;           sidx = 0;              unit = true;  }

    float acc = 0.f;
    int p = pb;
    const int pe = pb + dg;

    for (; p + 4 <= pe; p += 4) {
        int   s[4];
        float e0[4], e1[4], e2[4], e3[4], e4[4], e5[4], e6[4], fac[4];
#pragma unroll
        for (int k = 0; k < 4; ++k) {
            const float* row = edat + (size_t)(p + k) * 16;   // uniform -> scalar
            s[k]  = ((const int*)row)[7];
            e0[k] = row[0]; e1[k] = row[1]; e2[k] = row[2]; e3[k] = row[3];
            e4[k] = row[4]; e5[k] = row[5]; e6[k] = row[6];
            const float sv = row[8 + sidx];                   // per-lane small load
            fac[k] = unit ? 1.f : sv;
        }
        float z[4][7];
#pragma unroll
        for (int k = 0; k < 4; ++k) {
            const float* zt = Ztab + (size_t)s[k] * ZS + col;
#pragma unroll
            for (int j = 0; j < 7; ++j) z[k][j] = zt[j * 21];
        }
#pragma unroll
        for (int k = 0; k < 4; ++k) {
            const float t7 = e0[k]*z[k][0] + e1[k]*z[k][1] + e2[k]*z[k][2]
                           + e3[k]*z[k][3] + e4[k]*z[k][4] + e5[k]*z[k][5]
                           + e6[k]*z[k][6];
            acc += fac[k] * t7;
        }
    }
    for (; p < pe; ++p) {
        const float* row = edat + (size_t)p * 16;
        const int s = ((const int*)row)[7];
        const float sv = row[8 + sidx];
        const float fac = unit ? 1.f : sv;
        const float* zt = Ztab + (size_t)s * ZS + col;
        const float t7 = row[0]*zt[0]  + row[1]*zt[21] + row[2]*zt[42]
                       + row[3]*zt[63] + row[4]*zt[84] + row[5]*zt[105]
                       + row[6]*zt[126];
        acc += fac * t7;
    }

    rtab[(size_t)node * 64 + lane] = (lane < 63) ? acc : 0.f;
}

// ---------------- K4: per-edge g via rtab -> LDS graph bins -> out ----------------

__global__ __launch_bounds__(256) void k_gfinal(const float* __restrict__ pos,
                                                const float* __restrict__ eag,
                                                const int* __restrict__ esrc,
                                                const int* __restrict__ edst,
                                                const int* __restrict__ batch,
                                                const float* __restrict__ rtab,
                                                float* __restrict__ out)
{
    __shared__ float bins[NG];
    const int t = threadIdx.x;
    bins[t] = 0.f;
    __syncthreads();

    const int e0 = blockIdx.x * 1024;
    for (int it = 0; it < 4; ++it) {
        const int e = e0 + it * 256 + t;
        if (e < NE) {
            const int s = esrc[e], d = edst[e];
            float ea[7];
#pragma unroll
            for (int v = 0; v < 7; ++v) ea[v] = eag[(size_t)e * 7 + v];
            const float px = pos[3*s+0] - pos[3*d+0];
            const float py = pos[3*s+1] - pos[3*d+1];
            const float pz = pos[3*s+2] - pos[3*d+2];
            const float r2 = px*px + py*py + pz*pz;
            const float s10 = 1.7320508f*px, s11 = 1.7320508f*py, s12 = 1.7320508f*pz;
            const float s20 = 3.8729833f*px*py, s21 = 3.8729833f*py*pz,
                        s22 = 1.1180340f*(3.f*pz*pz - r2), s23 = 3.8729833f*px*pz,
                        s24 = 1.9364917f*(px*px - py*py);

            float rb[64];
            const float4* rr = (const float4*)(rtab + (size_t)s * 64);
#pragma unroll
            for (int i = 0; i < 16; ++i) *(float4*)&rb[4*i] = rr[i];

            float g = 0.f;
#pragma unroll
            for (int v = 0; v < 7; ++v) {
                const float tv = rb[v]
                               + s10*rb[7+v]  + s11*rb[14+v] + s12*rb[21+v]
                               + s20*rb[28+v] + s21*rb[35+v] + s22*rb[42+v]
                               + s23*rb[49+v] + s24*rb[56+v];
                g += ea[v] * tv;
            }
            atomicAdd(&bins[batch[d]], g);   // LDS atomic
        }
    }
    __syncthreads();
    unsafeAtomicAdd(&out[t], bins[t]);
}

extern "C" void kernel_launch(void* const* d_in, const int* in_sizes, int n_in,
                              void* d_out, int out_size, void* d_ws, size_t ws_size,
                              hipStream_t stream)
{
    const float* pos  = (const float*)d_in[0];
    const float* x    = (const float*)d_in[1];
    const float* eag  = (const float*)d_in[2];
    const int*   eidx = (const int*)d_in[3];
    const int*   batch= (const int*)d_in[4];
    const float* W1   = (const float*)d_in[5];
    const float* W2   = (const float*)d_in[6];
    const float* W3   = (const float*)d_in[7];
    const float* V1   = (const float*)d_in[8];
    const float* V2   = (const float*)d_in[9];
    const float* V3   = (const float*)d_in[10];
    const int* esrc = eidx;
    const int* edst = eidx + NE;

    char* ws = (char*)d_ws;
    size_t off = 0;
    auto alloc = [&](size_t bytes) -> void* {
        void* p = ws + off;
        off = (off + bytes + 255) & ~(size_t)255;
        return p;
    };
    float* edat = (float*)alloc((size_t)NN * CAP * 16 * sizeof(float));  // 81.9 MB
    float* Ztab = (float*)alloc((size_t)NN * ZS * sizeof(float));        // 11.8 MB
    float* rtab = (float*)alloc((size_t)NN * 64 * sizeof(float));        // 5.1 MB
    float* WV   = (float*)alloc((size_t)23 * 147 * sizeof(float));       // 13.5 KB
    int*   deg  = (int*)alloc((size_t)NN * sizeof(int));                 // 80 KB, zeroed

    hipMemsetAsync(deg, 0, (size_t)NN * sizeof(int), stream);
    hipMemsetAsync(d_out, 0, (size_t)NG * sizeof(float), stream);

    k_fill_wv<<<1250 + 14, 256, 0, stream>>>(pos, eag, esrc, edst,
                                             W1, W2, W3, V1, V2, V3,
                                             deg, edat, WV);
    k_ztab<<<2500, 256, 0, stream>>>(x, WV, Ztab);
    k_edge_acc<<<NN/4, 256, 0, stream>>>(Ztab, deg, edat, rtab);
    k_gfinal<<<(NE + 1023)/1024, 256, 0, stream>>>(pos, eag, esrc, edst, batch,
                                                   rtab, (float*)d_out);
}

// Round 16
// 219.431 us; speedup vs baseline: 1.7163x; 1.0031x over previous
//
#include <hip/hip_runtime.h>

#define NN 20000
#define NE 320000
#define NG 256
#define CAP 64            // dst bucket capacity; deg ~ Poisson(16), P(>64) ~ 1e-20
#define ZS 148            // Ztab row stride (147 used)

// edat row (16 floats = 64 B): [ea(7) | src(int) | sh1(3) | sh2(5)]

// ---------------- K1: blocks <1250 fill dst buckets; rest build WV ----------------
// WV[u][c], c = v'*21 + g*7 + v : a1*c_g * sum_w W_g[u,v',w] * V_g[w,v]

__global__ __launch_bounds__(256) void k_fill_wv(
    const float* __restrict__ pos,
    const float* __restrict__ eag,
    const int* __restrict__ esrc,
    const int* __restrict__ edst,
    const float* __restrict__ W1,
    const float* __restrict__ W2,
    const float* __restrict__ W3,
    const float* __restrict__ V1,
    const float* __restrict__ V2,
    const float* __restrict__ V3,
    int* __restrict__ deg,
    float* __restrict__ edat,
    float* __restrict__ WV)
{
    const int b = blockIdx.x, t = threadIdx.x;
    if (b < 1250) {
        const int e = b * 256 + t;          // 1250*256 == NE
        const int s = esrc[e], d = edst[e];
        const int slot = atomicAdd(&deg[d], 1);
        if (slot < CAP) {
            const int p = d * CAP + slot;
            float* o = edat + (size_t)p * 16;
#pragma unroll
            for (int v = 0; v < 7; ++v) o[v] = eag[(size_t)e * 7 + v];
            ((int*)o)[7] = s;
            const float px = pos[3*s+0] - pos[3*d+0];
            const float py = pos[3*s+1] - pos[3*d+1];
            const float pz = pos[3*s+2] - pos[3*d+2];
            const float r2 = px*px + py*py + pz*pz;
            o[8]  = 1.7320508f*px;
            o[9]  = 1.7320508f*py;
            o[10] = 1.7320508f*pz;
            o[11] = 3.8729833f*px*py;
            o[12] = 3.8729833f*py*pz;
            o[13] = 1.1180340f*(3.f*pz*pz - r2);
            o[14] = 3.8729833f*px*pz;
            o[15] = 1.9364917f*(px*px - py*py);
        }
    } else {
        const int idx = (b - 1250) * 256 + t;
        if (idx < 23 * 147) {
            const int u = idx / 147, c = idx - u * 147;
            const int vp = c / 21, col = c - vp * 21;
            const int g = col / 7, v = col - g * 7;
            float sum = 0.f;
            if (g == 0) {
                for (int w = 0; w < 64; ++w)
                    sum += W1[(u*7 + vp)*64 + w] * V1[w*7 + v];
                sum *= 0.07881104f * 0.04724556f;   // a1 * 1/sqrt(64*7)
            } else if (g == 1) {
                for (int w = 0; w < 24; ++w)
                    sum += W2[(u*7 + vp)*24 + w] * V2[w*7 + v];
                sum *= 0.07881104f * 0.04454354f;   // a1 * 1/sqrt(24*7*3)
            } else {
                for (int w = 0; w < 16; ++w)
                    sum += W3[(u*7 + vp)*16 + w] * V3[w*7 + v];
                sum *= 0.07881104f * 0.04225771f;   // a1 * 1/sqrt(16*7*5)
            }
            WV[idx] = sum;                           // [u][147] row-major
        }
    }
}

// ---------------- K2: Ztab[n][c] = sum_u x[n][u] * WV[u][c]  (8 nodes/block) ----------------

__global__ __launch_bounds__(256) void k_ztab(const float* __restrict__ x,
                                              const float* __restrict__ WV,
                                              float* __restrict__ Ztab)
{
    __shared__ float xa[8][23];
    const int b = blockIdx.x, t = threadIdx.x;   // grid 2500 exact
    const int base = b * 8;
    if (t < 184) {
        const int nl = t / 23, u = t - nl * 23;
        xa[nl][u] = x[(size_t)(base + nl) * 23 + u];
    }
    __syncthreads();
    if (t < 147) {
        float acc[8];
#pragma unroll
        for (int n = 0; n < 8; ++n) acc[n] = 0.f;
        for (int u = 0; u < 23; ++u) {
            const float wv = WV[u * 147 + t];     // coalesced
#pragma unroll
            for (int n = 0; n < 8; ++n) acc[n] += xa[n][u] * wv;
        }
#pragma unroll
        for (int n = 0; n < 8; ++n)
            Ztab[(size_t)(base + n) * ZS + t] = acc[n];
    }
}

// ---------------- K3: wave per dst node; edat staged in LDS; z gathers pipelined 1 chunk ahead ----
// rtab row (64 fp32): [r0[v](7) | r1[m,v] m-major (21) | r2[m,v] m-major (35) | pad]

__global__ __launch_bounds__(256) void k_edge_acc(const float* __restrict__ Ztab,
                                                  const int* __restrict__ deg,
                                                  const float* __restrict__ edat,
                                                  float* __restrict__ rtab)
{
    __shared__ __align__(16) float edl[4][CAP * 16];   // 16 KB: per-wave edge bucket
    const int t = threadIdx.x, lane = t & 63;
    const int wid = __builtin_amdgcn_readfirstlane(t >> 6);
    const int node = __builtin_amdgcn_readfirstlane(blockIdx.x * 4 + wid);
    const int dg = min(deg[node], CAP);
    const int nch = (dg + 3) >> 2;
    const int dgp = nch << 2;                 // padded to chunk multiple

    // cooperative stage: dg rows (4 float4 each), then zero the pad rows
    {
        const float4* src = (const float4*)(edat + (size_t)node * (CAP * 16));
        float4* dst = (float4*)edl[wid];
        for (int i = lane; i < dg * 4; i += 64) dst[i] = src[i];
        const float4 z4 = make_float4(0.f, 0.f, 0.f, 0.f);
        for (int i = dg * 4 + lane; i < dgp * 4; i += 64) dst[i] = z4;
    }
    // (same-wave LDS RAW: compiler inserts lgkmcnt/vmcnt waits; no barrier needed)

    // per-lane constants
    int col, sidx; bool unit;
    if (lane < 7)       { col = lane;              sidx = 0;          unit = true;  }
    else if (lane < 28) { const int i = lane - 7;  col = 7  + i % 7;  sidx = i / 7;     unit = false; }
    else if (lane < 63) { const int i = lane - 28; col = 14 + i % 7;  sidx = 3 + i / 7; unit = false; }
    else                { col = 0;                 sidx = 0;          unit = true;  }

    const float* el = edl[wid];
    float acc = 0.f;
    float zc[4][7];
    int   sc[4];

    if (nch > 0) {
        // prologue: s + z for chunk 0
#pragma unroll
        for (int k = 0; k < 4; ++k) sc[k] = ((const int*)(el + k * 16))[7];
#pragma unroll
        for (int k = 0; k < 4; ++k) {
            const float* zt = Ztab + (size_t)sc[k] * ZS + col;
#pragma unroll
            for (int j = 0; j < 7; ++j) zc[k][j] = zt[j * 21];
        }
    }

    for (int c = 0; c < nch; ++c) {
        const bool more = (c + 1) < nch;
        int   sn[4];
        float zn[4][7];
        if (more) {
            // issue next chunk's gathers before consuming current (z latency hidden)
#pragma unroll
            for (int k = 0; k < 4; ++k) sn[k] = ((const int*)(el + (4*(c+1) + k) * 16))[7];
#pragma unroll
            for (int k = 0; k < 4; ++k) {
                const float* zt = Ztab + (size_t)sn[k] * ZS + col;
#pragma unroll
                for (int j = 0; j < 7; ++j) zn[k][j] = zt[j * 21];
            }
        }
        // compute current chunk: ea/fac from LDS (broadcast reads), z from regs
#pragma unroll
        for (int k = 0; k < 4; ++k) {
            const float* row = el + (4*c + k) * 16;
            const float t7 = row[0]*zc[k][0] + row[1]*zc[k][1] + row[2]*zc[k][2]
                           + row[3]*zc[k][3] + row[4]*zc[k][4] + row[5]*zc[k][5]
                           + row[6]*zc[k][6];
            const float sv = row[8 + sidx];
            acc += (unit ? 1.f : sv) * t7;
        }
        if (more) {
#pragma unroll
            for (int k = 0; k < 4; ++k) {
                sc[k] = sn[k];
#pragma unroll
                for (int j = 0; j < 7; ++j) zc[k][j] = zn[k][j];
            }
        }
    }

    rtab[(size_t)node * 64 + lane] = (lane < 63) ? acc : 0.f;
}

// ---------------- K4: per-edge g via rtab -> LDS graph bins -> out ----------------

__global__ __launch_bounds__(256) void k_gfinal(const float* __restrict__ pos,
                                                const float* __restrict__ eag,
                                                const int* __restrict__ esrc,
                                                const int* __restrict__ edst,
                                                const int* __restrict__ batch,
                                                const float* __restrict__ rtab,
                                                float* __restrict__ out)
{
    __shared__ float bins[NG];
    const int t = threadIdx.x;
    bins[t] = 0.f;
    __syncthreads();

    const int e0 = blockIdx.x * 1024;
    for (int it = 0; it < 4; ++it) {
        const int e = e0 + it * 256 + t;
        if (e < NE) {
            const int s = esrc[e], d = edst[e];
            float ea[7];
#pragma unroll
            for (int v = 0; v < 7; ++v) ea[v] = eag[(size_t)e * 7 + v];
            const float px = pos[3*s+0] - pos[3*d+0];
            const float py = pos[3*s+1] - pos[3*d+1];
            const float pz = pos[3*s+2] - pos[3*d+2];
            const float r2 = px*px + py*py + pz*pz;
            const float s10 = 1.7320508f*px, s11 = 1.7320508f*py, s12 = 1.7320508f*pz;
            const float s20 = 3.8729833f*px*py, s21 = 3.8729833f*py*pz,
                        s22 = 1.1180340f*(3.f*pz*pz - r2), s23 = 3.8729833f*px*pz,
                        s24 = 1.9364917f*(px*px - py*py);

            float rb[64];
            const float4* rr = (const float4*)(rtab + (size_t)s * 64);
#pragma unroll
            for (int i = 0; i < 16; ++i) *(float4*)&rb[4*i] = rr[i];

            float g = 0.f;
#pragma unroll
            for (int v = 0; v < 7; ++v) {
                const float tv = rb[v]
                               + s10*rb[7+v]  + s11*rb[14+v] + s12*rb[21+v]
                               + s20*rb[28+v] + s21*rb[35+v] + s22*rb[42+v]
                               + s23*rb[49+v] + s24*rb[56+v];
                g += ea[v] * tv;
            }
            atomicAdd(&bins[batch[d]], g);   // LDS atomic
        }
    }
    __syncthreads();
    unsafeAtomicAdd(&out[t], bins[t]);
}

extern "C" void kernel_launch(void* const* d_in, const int* in_sizes, int n_in,
                              void* d_out, int out_size, void* d_ws, size_t ws_size,
                              hipStream_t stream)
{
    const float* pos  = (const float*)d_in[0];
    const float* x    = (const float*)d_in[1];
    const float* eag  = (const float*)d_in[2];
    const int*   eidx = (const int*)d_in[3];
    const int*   batch= (const int*)d_in[4];
    const float* W1   = (const float*)d_in[5];
    const float* W2   = (const float*)d_in[6];
    const float* W3   = (const float*)d_in[7];
    const float* V1   = (const float*)d_in[8];
    const float* V2   = (const float*)d_in[9];
    const float* V3   = (const float*)d_in[10];
    const int* esrc = eidx;
    const int* edst = eidx + NE;

    char* ws = (char*)d_ws;
    size_t off = 0;
    auto alloc = [&](size_t bytes) -> void* {
        void* p = ws + off;
        off = (off + bytes + 255) & ~(size_t)255;
        return p;
    };
    float* edat = (float*)alloc((size_t)NN * CAP * 16 * sizeof(float));  // 81.9 MB
    float* Ztab = (float*)alloc((size_t)NN * ZS * sizeof(float));        // 11.8 MB
    float* rtab = (float*)alloc((size_t)NN * 64 * sizeof(float));        // 5.1 MB
    float* WV   = (float*)alloc((size_t)23 * 147 * sizeof(float));       // 13.5 KB
    int*   deg  = (int*)alloc((size_t)NN * sizeof(int));                 // 80 KB, zeroed

    hipMemsetAsync(deg, 0, (size_t)NN * sizeof(int), stream);
    hipMemsetAsync(d_out, 0, (size_t)NG * sizeof(float), stream);

    k_fill_wv<<<1250 + 14, 256, 0, stream>>>(pos, eag, esrc, edst,
                                             W1, W2, W3, V1, V2, V3,
                                             deg, edat, WV);
    k_ztab<<<2500, 256, 0, stream>>>(x, WV, Ztab);
    k_edge_acc<<<NN/4, 256, 0, stream>>>(Ztab, deg, edat, rtab);
    k_gfinal<<<(NE + 1023)/1024, 256, 0, stream>>>(pos, eag, esrc, edst, batch,
                                                   rtab, (float*)d_out);
}

// Round 17
// 204.063 us; speedup vs baseline: 1.8456x; 1.0753x over previous
//
#include <hip/hip_runtime.h>

#define NN 20000
#define NE 320000
#define NG 256
#define CAP 64            // dst bucket capacity; deg ~ Poisson(16), P(>64) ~ 1e-20
#define ZS 148            // Ztab row stride (147 used)

// edat row (16 floats = 64 B): [ea(7) | src(int) | sh1(3) | sh2(5)]
// y row (21 floats): y[col], col = g*7+v, scale factors folded via WV

// ---------------- K1: blocks <1250 fill dst buckets + pmap; rest build WV ----------------
// WV[u][c], c = v'*21 + g*7 + v : a1*c_g * sum_w W_g[u,v',w] * V_g[w,v]

__global__ __launch_bounds__(256) void k_fill_wv(
    const float* __restrict__ pos,
    const float* __restrict__ eag,
    const int* __restrict__ esrc,
    const int* __restrict__ edst,
    const float* __restrict__ W1,
    const float* __restrict__ W2,
    const float* __restrict__ W3,
    const float* __restrict__ V1,
    const float* __restrict__ V2,
    const float* __restrict__ V3,
    int* __restrict__ deg,
    float* __restrict__ edat,
    int* __restrict__ pmap,
    float* __restrict__ WV)
{
    const int b = blockIdx.x, t = threadIdx.x;
    if (b < 1250) {
        const int e = b * 256 + t;          // 1250*256 == NE
        const int s = esrc[e], d = edst[e];
        const int slot = atomicAdd(&deg[d], 1);
        if (slot < CAP) {
            const int p = d * CAP + slot;
            pmap[e] = p;
            float* o = edat + (size_t)p * 16;
#pragma unroll
            for (int v = 0; v < 7; ++v) o[v] = eag[(size_t)e * 7 + v];
            ((int*)o)[7] = s;
            const float px = pos[3*s+0] - pos[3*d+0];
            const float py = pos[3*s+1] - pos[3*d+1];
            const float pz = pos[3*s+2] - pos[3*d+2];
            const float r2 = px*px + py*py + pz*pz;
            o[8]  = 1.7320508f*px;
            o[9]  = 1.7320508f*py;
            o[10] = 1.7320508f*pz;
            o[11] = 3.8729833f*px*py;
            o[12] = 3.8729833f*py*pz;
            o[13] = 1.1180340f*(3.f*pz*pz - r2);
            o[14] = 3.8729833f*px*pz;
            o[15] = 1.9364917f*(px*px - py*py);
        } else {
            pmap[e] = -1;
        }
    } else {
        const int idx = (b - 1250) * 256 + t;
        if (idx < 23 * 147) {
            const int u = idx / 147, c = idx - u * 147;
            const int vp = c / 21, col = c - vp * 21;
            const int g = col / 7, v = col - g * 7;
            float sum = 0.f;
            if (g == 0) {
                for (int w = 0; w < 64; ++w)
                    sum += W1[(u*7 + vp)*64 + w] * V1[w*7 + v];
                sum *= 0.07881104f * 0.04724556f;   // a1 * 1/sqrt(64*7)
            } else if (g == 1) {
                for (int w = 0; w < 24; ++w)
                    sum += W2[(u*7 + vp)*24 + w] * V2[w*7 + v];
                sum *= 0.07881104f * 0.04454354f;   // a1 * 1/sqrt(24*7*3)
            } else {
                for (int w = 0; w < 16; ++w)
                    sum += W3[(u*7 + vp)*16 + w] * V3[w*7 + v];
                sum *= 0.07881104f * 0.04225771f;   // a1 * 1/sqrt(16*7*5)
            }
            WV[idx] = sum;                           // [u][147] row-major
        }
    }
}

// ---------------- K2: Ztab[n][c] = sum_u x[n][u] * WV[u][c]  (8 nodes/block) ----------------

__global__ __launch_bounds__(256) void k_ztab(const float* __restrict__ x,
                                              const float* __restrict__ WV,
                                              float* __restrict__ Ztab)
{
    __shared__ float xa[8][23];
    const int b = blockIdx.x, t = threadIdx.x;   // grid 2500 exact
    const int base = b * 8;
    if (t < 184) {
        const int nl = t / 23, u = t - nl * 23;
        xa[nl][u] = x[(size_t)(base + nl) * 23 + u];
    }
    __syncthreads();
    if (t < 147) {
        float acc[8];
#pragma unroll
        for (int n = 0; n < 8; ++n) acc[n] = 0.f;
        for (int u = 0; u < 23; ++u) {
            const float wv = WV[u * 147 + t];     // coalesced
#pragma unroll
            for (int n = 0; n < 8; ++n) acc[n] += xa[n][u] * wv;
        }
#pragma unroll
        for (int n = 0; n < 8; ++n)
            Ztab[(size_t)(base + n) * ZS + t] = acc[n];
    }
}

// ---------------- K3: edge-parallel y; lane = (edge, col); fully independent lanes ----------------
// y[p][col] = sum_j ea[j] * Ztab[src][j*21 + col]

__global__ __launch_bounds__(256) void k_yedge(const float* __restrict__ Ztab,
                                               const float* __restrict__ edat,
                                               const int* __restrict__ pmap,
                                               float* __restrict__ yq)
{
    const int gid = blockIdx.x * 256 + threadIdx.x;
    const int e = gid / 21, col = gid - e * 21;
    if (e >= NE) return;
    const int p = pmap[e];
    if (p < 0) return;
    const float* row = edat + (size_t)p * 16;
    const int s = ((const int*)row)[7];
    const float* zt = Ztab + (size_t)s * ZS + col;
    // issue all loads (ea row is L1-hot; z are the 7 real gathers, independent)
    const float y = row[0]*zt[0]   + row[1]*zt[21]  + row[2]*zt[42]
                  + row[3]*zt[63]  + row[4]*zt[84]  + row[5]*zt[105]
                  + row[6]*zt[126];
    yq[(size_t)p * 21 + col] = y;
}

// ---------------- K4: wave per dst node; streaming reduction of its bucket (no gathers) ----------
// rtab row (64 fp32): [r0[v](7) | r1[m,v] m-major (21) | r2[m,v] m-major (35) | pad]

__global__ __launch_bounds__(256) void k_racc(const float* __restrict__ yq,
                                              const int* __restrict__ deg,
                                              const float* __restrict__ edat,
                                              float* __restrict__ rtab)
{
    const int t = threadIdx.x, lane = t & 63;
    const int node = __builtin_amdgcn_readfirstlane(blockIdx.x * 4 + (t >> 6));
    const int dg = min(deg[node], CAP);

    int col, sidx; bool unit;
    if (lane < 7)       { col = lane;              sidx = 0;          unit = true;  }
    else if (lane < 28) { const int i = lane - 7;  col = 7  + i % 7;  sidx = i / 7;     unit = false; }
    else if (lane < 63) { const int i = lane - 28; col = 14 + i % 7;  sidx = 3 + i / 7; unit = false; }
    else                { col = 0;                 sidx = 0;          unit = true;  }

    const float* yb = yq   + (size_t)node * (CAP * 21);
    const float* eb = edat + (size_t)node * (CAP * 16);

    float acc = 0.f;
    int r = 0;
    for (; r + 4 <= dg; r += 4) {
        float yv[4], sv[4];
#pragma unroll
        for (int k = 0; k < 4; ++k) yv[k] = yb[(r + k) * 21 + col];
#pragma unroll
        for (int k = 0; k < 4; ++k) sv[k] = eb[(r + k) * 16 + 8 + sidx];
#pragma unroll
        for (int k = 0; k < 4; ++k) acc += (unit ? 1.f : sv[k]) * yv[k];
    }
    for (; r < dg; ++r) {
        const float yv = yb[r * 21 + col];
        const float sv = eb[r * 16 + 8 + sidx];
        acc += (unit ? 1.f : sv) * yv;
    }

    rtab[(size_t)node * 64 + lane] = (lane < 63) ? acc : 0.f;
}

// ---------------- K5: per-edge g via rtab -> LDS graph bins -> out ----------------

__global__ __launch_bounds__(256) void k_gfinal(const float* __restrict__ pos,
                                                const float* __restrict__ eag,
                                                const int* __restrict__ esrc,
                                                const int* __restrict__ edst,
                                                const int* __restrict__ batch,
                                                const float* __restrict__ rtab,
                                                float* __restrict__ out)
{
    __shared__ float bins[NG];
    const int t = threadIdx.x;
    bins[t] = 0.f;
    __syncthreads();

    const int e0 = blockIdx.x * 1024;
    for (int it = 0; it < 4; ++it) {
        const int e = e0 + it * 256 + t;
        if (e < NE) {
            const int s = esrc[e], d = edst[e];
            float ea[7];
#pragma unroll
            for (int v = 0; v < 7; ++v) ea[v] = eag[(size_t)e * 7 + v];
            const float px = pos[3*s+0] - pos[3*d+0];
            const float py = pos[3*s+1] - pos[3*d+1];
            const float pz = pos[3*s+2] - pos[3*d+2];
            const float r2 = px*px + py*py + pz*pz;
            const float s10 = 1.7320508f*px, s11 = 1.7320508f*py, s12 = 1.7320508f*pz;
            const float s20 = 3.8729833f*px*py, s21 = 3.8729833f*py*pz,
                        s22 = 1.1180340f*(3.f*pz*pz - r2), s23 = 3.8729833f*px*pz,
                        s24 = 1.9364917f*(px*px - py*py);

            float rb[64];
            const float4* rr = (const float4*)(rtab + (size_t)s * 64);
#pragma unroll
            for (int i = 0; i < 16; ++i) *(float4*)&rb[4*i] = rr[i];

            float g = 0.f;
#pragma unroll
            for (int v = 0; v < 7; ++v) {
                const float tv = rb[v]
                               + s10*rb[7+v]  + s11*rb[14+v] + s12*rb[21+v]
                               + s20*rb[28+v] + s21*rb[35+v] + s22*rb[42+v]
                               + s23*rb[49+v] + s24*rb[56+v];
                g += ea[v] * tv;
            }
            atomicAdd(&bins[batch[d]], g);   // LDS atomic
        }
    }
    __syncthreads();
    unsafeAtomicAdd(&out[t], bins[t]);
}

extern "C" void kernel_launch(void* const* d_in, const int* in_sizes, int n_in,
                              void* d_out, int out_size, void* d_ws, size_t ws_size,
                              hipStream_t stream)
{
    const float* pos  = (const float*)d_in[0];
    const float* x    = (const float*)d_in[1];
    const float* eag  = (const float*)d_in[2];
    const int*   eidx = (const int*)d_in[3];
    const int*   batch= (const int*)d_in[4];
    const float* W1   = (const float*)d_in[5];
    const float* W2   = (const float*)d_in[6];
    const float* W3   = (const float*)d_in[7];
    const float* V1   = (const float*)d_in[8];
    const float* V2   = (const float*)d_in[9];
    const float* V3   = (const float*)d_in[10];
    const int* esrc = eidx;
    const int* edst = eidx + NE;

    char* ws = (char*)d_ws;
    size_t off = 0;
    auto alloc = [&](size_t bytes) -> void* {
        void* p = ws + off;
        off = (off + bytes + 255) & ~(size_t)255;
        return p;
    };
    float* edat = (float*)alloc((size_t)NN * CAP * 16 * sizeof(float));  // 81.9 MB
    float* yq   = (float*)alloc((size_t)NN * CAP * 21 * sizeof(float));  // 107.5 MB
    float* Ztab = (float*)alloc((size_t)NN * ZS * sizeof(float));        // 11.8 MB
    float* rtab = (float*)alloc((size_t)NN * 64 * sizeof(float));        // 5.1 MB
    int*   pmap = (int*)alloc((size_t)NE * sizeof(int));                 // 1.28 MB
    float* WV   = (float*)alloc((size_t)23 * 147 * sizeof(float));       // 13.5 KB
    int*   deg  = (int*)alloc((size_t)NN * sizeof(int));                 // 80 KB, zeroed

    hipMemsetAsync(deg, 0, (size_t)NN * sizeof(int), stream);
    hipMemsetAsync(d_out, 0, (size_t)NG * sizeof(float), stream);

    k_fill_wv<<<1250 + 14, 256, 0, stream>>>(pos, eag, esrc, edst,
                                             W1, W2, W3, V1, V2, V3,
                                             deg, edat, pmap, WV);
    k_ztab<<<2500, 256, 0, stream>>>(x, WV, Ztab);
    k_yedge<<<(NE * 21 + 255) / 256, 256, 0, stream>>>(Ztab, edat, pmap, yq);
    k_racc<<<NN/4, 256, 0, stream>>>(yq, deg, edat, rtab);
    k_gfinal<<<(NE + 1023)/1024, 256, 0, stream>>>(pos, eag, esrc, edst, batch,
                                                   rtab, (float*)d_out);
}

// Round 18
// 188.265 us; speedup vs baseline: 2.0005x; 1.0839x over previous
//
#include <hip/hip_runtime.h>

#define NN 20000
#define NE 320000
#define NG 256
#define CAP 64            // bucket capacity per node (both sides); deg ~ Poisson(16)
#define ZS 148            // Ztab row stride (147 used)

// edat_s row (16 floats): [ea(7) | (p | bg<<21) as int | sh1(3) sh2(5)]
// edat_d row (8 floats):  [sh1(3) sh2(5)]
// y row (21 floats): y[col], col = g*7+v, scale factors folded via WV

// ---------------- K1: blocks <1250 fill both buckets; rest build WV ----------------

__global__ __launch_bounds__(256) void k_fill_wv(
    const float* __restrict__ pos,
    const float* __restrict__ eag,
    const int* __restrict__ esrc,
    const int* __restrict__ edst,
    const int* __restrict__ batch,
    const float* __restrict__ W1,
    const float* __restrict__ W2,
    const float* __restrict__ W3,
    const float* __restrict__ V1,
    const float* __restrict__ V2,
    const float* __restrict__ V3,
    int* __restrict__ deg_d,
    int* __restrict__ deg_s,
    float* __restrict__ edat_d,
    float* __restrict__ edat_s,
    float* __restrict__ WV)
{
    const int b = blockIdx.x, t = threadIdx.x;
    if (b < 1250) {
        const int e = b * 256 + t;          // 1250*256 == NE
        const int s = esrc[e], d = edst[e];
        const int slot_d = atomicAdd(&deg_d[d], 1);
        if (slot_d < CAP) {
            const int p = d * CAP + slot_d;
            const float px = pos[3*s+0] - pos[3*d+0];
            const float py = pos[3*s+1] - pos[3*d+1];
            const float pz = pos[3*s+2] - pos[3*d+2];
            const float r2 = px*px + py*py + pz*pz;
            const float4 sh0 = make_float4(1.7320508f*px, 1.7320508f*py,
                                           1.7320508f*pz, 3.8729833f*px*py);
            const float4 sh1 = make_float4(3.8729833f*py*pz,
                                           1.1180340f*(3.f*pz*pz - r2),
                                           3.8729833f*px*pz,
                                           1.9364917f*(px*px - py*py));
            float4* od = (float4*)(edat_d + (size_t)p * 8);
            od[0] = sh0; od[1] = sh1;

            const int slot_s = atomicAdd(&deg_s[s], 1);
            if (slot_s < CAP) {
                const int q = s * CAP + slot_s;
                const int pk = p | (batch[d] << 21);   // p < 2^21
                const float* ear = eag + (size_t)e * 7;
                float4* os = (float4*)(edat_s + (size_t)q * 16);
                os[0] = make_float4(ear[0], ear[1], ear[2], ear[3]);
                os[1] = make_float4(ear[4], ear[5], ear[6], __int_as_float(pk));
                os[2] = sh0; os[3] = sh1;
            }
        }
    } else {
        const int idx = (b - 1250) * 256 + t;   // WV: 23*147
        if (idx < 23 * 147) {
            const int u = idx / 147, c = idx - u * 147;
            const int vp = c / 21, col = c - vp * 21;
            const int g = col / 7, v = col - g * 7;
            float sum = 0.f;
            if (g == 0) {
                for (int w = 0; w < 64; ++w)
                    sum += W1[(u*7 + vp)*64 + w] * V1[w*7 + v];
                sum *= 0.07881104f * 0.04724556f;   // a1 * 1/sqrt(64*7)
            } else if (g == 1) {
                for (int w = 0; w < 24; ++w)
                    sum += W2[(u*7 + vp)*24 + w] * V2[w*7 + v];
                sum *= 0.07881104f * 0.04454354f;   // a1 * 1/sqrt(24*7*3)
            } else {
                for (int w = 0; w < 16; ++w)
                    sum += W3[(u*7 + vp)*16 + w] * V3[w*7 + v];
                sum *= 0.07881104f * 0.04225771f;   // a1 * 1/sqrt(16*7*5)
            }
            WV[idx] = sum;                           // [u][147], c = v'*21 + col
        }
    }
}

// ---------------- K2: Ztab[n][c] = sum_u x[n][u] * WV[u][c]  (8 nodes/block) ----------------

__global__ __launch_bounds__(256) void k_ztab(const float* __restrict__ x,
                                              const float* __restrict__ WV,
                                              float* __restrict__ Ztab)
{
    __shared__ float xa[8][23];
    const int b = blockIdx.x, t = threadIdx.x;   // grid 2500 exact
    const int base = b * 8;
    if (t < 184) {
        const int nl = t / 23, u = t - nl * 23;
        xa[nl][u] = x[(size_t)(base + nl) * 23 + u];
    }
    __syncthreads();
    if (t < 147) {
        float acc[8];
#pragma unroll
        for (int n = 0; n < 8; ++n) acc[n] = 0.f;
        for (int u = 0; u < 23; ++u) {
            const float wv = WV[u * 147 + t];     // coalesced
#pragma unroll
            for (int n = 0; n < 8; ++n) acc[n] += xa[n][u] * wv;
        }
#pragma unroll
        for (int n = 0; n < 8; ++n)
            Ztab[(size_t)(base + n) * ZS + t] = acc[n];
    }
}

// ---------------- K3: wave per src node; Ztab row in LDS; 3 edges x 21 cols per iter ----------

__global__ __launch_bounds__(256) void k_yedge(const float* __restrict__ Ztab,
                                               const int* __restrict__ deg_s,
                                               const float* __restrict__ edat_s,
                                               float* __restrict__ yq)
{
    __shared__ float zl[4][ZS];
    const int t = threadIdx.x, lane = t & 63, w = t >> 6;
    const int s = __builtin_amdgcn_readfirstlane(blockIdx.x * 4 + w);  // grid 5000
    {
        const float* zr = Ztab + (size_t)s * ZS;
        for (int i = lane; i < ZS; i += 64) zl[w][i] = zr[i];
    }
    const int dg = min(deg_s[s], CAP);
    const int eo = lane / 21, col = lane - eo * 21;   // eo 0..2 active (lane 63 idle)
    const float* z = zl[w];

    for (int base = 0; base < dg; base += 3) {
        const int r = base + eo;
        if (eo < 3 && r < dg) {
            const float* row = edat_s + (size_t)(s * CAP + r) * 16;
            const float4 a0 = *(const float4*)row;         // ea0..3
            const float4 a1 = *(const float4*)(row + 4);   // ea4..6, pk
            const int p = __float_as_int(a1.w) & 0x1FFFFF;
            const float y = a0.x*z[col]      + a0.y*z[21+col]  + a0.z*z[42+col]
                          + a0.w*z[63+col]   + a1.x*z[84+col]  + a1.y*z[105+col]
                          + a1.z*z[126+col];
            yq[(size_t)p * 21 + col] = y;
        }
    }
}

// ---------------- K4: wave per dst node; streaming reduction of its bucket ----------------
// rtab row (64 fp32): [r0[v](7) | r1[m,v] m-major (21) | r2[m,v] m-major (35) | pad]

__global__ __launch_bounds__(256) void k_racc(const float* __restrict__ yq,
                                              const int* __restrict__ deg_d,
                                              const float* __restrict__ edat_d,
                                              float* __restrict__ rtab)
{
    const int t = threadIdx.x, lane = t & 63;
    const int node = __builtin_amdgcn_readfirstlane(blockIdx.x * 4 + (t >> 6));
    const int dg = min(deg_d[node], CAP);

    int col, sidx; bool unit;
    if (lane < 7)       { col = lane;              sidx = 0;          unit = true;  }
    else if (lane < 28) { const int i = lane - 7;  col = 7  + i % 7;  sidx = i / 7;     unit = false; }
    else if (lane < 63) { const int i = lane - 28; col = 14 + i % 7;  sidx = 3 + i / 7; unit = false; }
    else                { col = 0;                 sidx = 0;          unit = true;  }

    const float* yb = yq     + (size_t)node * (CAP * 21);
    const float* eb = edat_d + (size_t)node * (CAP * 8);

    float acc = 0.f;
    int r = 0;
    for (; r + 4 <= dg; r += 4) {
        float yv[4], sv[4];
#pragma unroll
        for (int k = 0; k < 4; ++k) yv[k] = yb[(r + k) * 21 + col];
#pragma unroll
        for (int k = 0; k < 4; ++k) sv[k] = eb[(r + k) * 8 + sidx];
#pragma unroll
        for (int k = 0; k < 4; ++k) acc += (unit ? 1.f : sv[k]) * yv[k];
    }
    for (; r < dg; ++r) {
        const float yv = yb[r * 21 + col];
        const float sv = eb[r * 8 + sidx];
        acc += (unit ? 1.f : sv) * yv;
    }

    rtab[(size_t)node * 64 + lane] = (lane < 63) ? acc : 0.f;
}

// ---------------- K5: wave per src node; rtab row in LDS; 9 edges x 7 v-lanes -> graph bins ----

__global__ __launch_bounds__(256) void k_gfinal(const float* __restrict__ rtab,
                                                const int* __restrict__ deg_s,
                                                const float* __restrict__ edat_s,
                                                float* __restrict__ partial)
{
    __shared__ float rl[4][64];
    __shared__ float bins[NG];
    const int t = threadIdx.x, lane = t & 63, w = t >> 6;
    bins[t] = 0.f;
    const int s = __builtin_amdgcn_readfirstlane(blockIdx.x * 4 + w);  // grid 5000
    rl[w][lane] = rtab[(size_t)s * 64 + lane];
    __syncthreads();

    const int dg = min(deg_s[s], CAP);
    const int eo = lane / 7, v = lane - eo * 7;   // 9 edges x 7 lanes, lane 63 idle
    const float* r = rl[w];

    for (int base = 0; base < dg; base += 9) {
        const int e = base + eo;
        if (lane < 63 && e < dg) {
            const float* row = edat_s + (size_t)(s * CAP + e) * 16;
            const float eav = row[v];
            const int bg = __float_as_int(row[7]) >> 21;
            float tsum = r[v];                        // shfac[0] = 1
#pragma unroll
            for (int k = 1; k < 9; ++k) tsum += row[7 + k] * r[k * 7 + v];
            atomicAdd(&bins[bg], eav * tsum);         // LDS atomic
        }
    }
    __syncthreads();
    unsafeAtomicAdd(&partial[(blockIdx.x & 15) * NG + t], bins[t]);
}

// ---------------- K6: reduce 16 partial rows -> out ----------------

__global__ __launch_bounds__(256) void k_reduce(const float* __restrict__ partial,
                                                float* __restrict__ out)
{
    const int t = threadIdx.x;
    float s = 0.f;
#pragma unroll
    for (int i = 0; i < 16; ++i) s += partial[i * NG + t];
    out[t] = s;
}

extern "C" void kernel_launch(void* const* d_in, const int* in_sizes, int n_in,
                              void* d_out, int out_size, void* d_ws, size_t ws_size,
                              hipStream_t stream)
{
    const float* pos  = (const float*)d_in[0];
    const float* x    = (const float*)d_in[1];
    const float* eag  = (const float*)d_in[2];
    const int*   eidx = (const int*)d_in[3];
    const int*   batch= (const int*)d_in[4];
    const float* W1   = (const float*)d_in[5];
    const float* W2   = (const float*)d_in[6];
    const float* W3   = (const float*)d_in[7];
    const float* V1   = (const float*)d_in[8];
    const float* V2   = (const float*)d_in[9];
    const float* V3   = (const float*)d_in[10];
    const int* esrc = eidx;
    const int* edst = eidx + NE;

    char* ws = (char*)d_ws;
    size_t off = 0;
    auto alloc = [&](size_t bytes) -> void* {
        void* p = ws + off;
        off = (off + bytes + 255) & ~(size_t)255;
        return p;
    };
    float* yq     = (float*)alloc((size_t)NN * CAP * 21 * sizeof(float));  // 107.5 MB
    float* edat_s = (float*)alloc((size_t)NN * CAP * 16 * sizeof(float));  // 81.9 MB
    float* edat_d = (float*)alloc((size_t)NN * CAP * 8 * sizeof(float));   // 41.0 MB
    float* Ztab   = (float*)alloc((size_t)NN * ZS * sizeof(float));        // 11.8 MB
    float* rtab   = (float*)alloc((size_t)NN * 64 * sizeof(float));        // 5.1 MB
    float* WV     = (float*)alloc((size_t)23 * 147 * sizeof(float));       // 13.5 KB
    int*   deg_d  = (int*)alloc((size_t)NN * sizeof(int));     // ---- zeroed region
    int*   deg_s  = (int*)alloc((size_t)NN * sizeof(int));
    float* partial= (float*)alloc((size_t)16 * NG * sizeof(float));
    char*  zend   = (char*)ws + off;

    hipMemsetAsync(deg_d, 0, (size_t)(zend - (char*)deg_d), stream);

    k_fill_wv<<<1250 + 14, 256, 0, stream>>>(pos, eag, esrc, edst, batch,
                                             W1, W2, W3, V1, V2, V3,
                                             deg_d, deg_s, edat_d, edat_s, WV);
    k_ztab<<<2500, 256, 0, stream>>>(x, WV, Ztab);
    k_yedge<<<NN/4, 256, 0, stream>>>(Ztab, deg_s, edat_s, yq);
    k_racc<<<NN/4, 256, 0, stream>>>(yq, deg_d, edat_d, rtab);
    k_gfinal<<<NN/4, 256, 0, stream>>>(rtab, deg_s, edat_s, partial);
    k_reduce<<<1, 256, 0, stream>>>(partial, (float*)d_out);
}